// Round 11
// baseline (254.936 us; speedup 1.0000x reference)
//
#include <hip/hip_runtime.h>
#include <math.h>

#define N_NODES 40000
#define N_EDGES 640000
#define HIDDEN 128
#define N_LAYERS 4
#define N_CLASSES 40
#define SCALING 0.08838834764831845f

typedef __attribute__((ext_vector_type(8))) short short8;
typedef __attribute__((ext_vector_type(4))) float floatx4;

static __device__ __forceinline__ float b2f(unsigned short u) {
  return __uint_as_float(((unsigned)u) << 16);
}
static __device__ __forceinline__ unsigned short f2b(float f) {
  unsigned u = __float_as_uint(f);
  u += 0x7fff + ((u >> 16) & 1);   // round-to-nearest-even
  return (unsigned short)(u >> 16);
}

// ---------------- setup: cast h0 -> bf16 g0, build CSR -------------------------
__global__ __launch_bounds__(256) void setup_all(
    const float* __restrict__ h_in, const int* __restrict__ dst,
    unsigned short* __restrict__ g0, int* __restrict__ row_start)
{
  int idx = blockIdx.x * 256 + threadIdx.x;
  if (idx < 640000) {                 // 40000*128/8 vector casts
    const float4* p = (const float4*)h_in + (size_t)idx * 2;
    float4 a = p[0], b = p[1];
    union { unsigned short us[8]; uint4 v; } o;
    o.us[0] = f2b(a.x); o.us[1] = f2b(a.y); o.us[2] = f2b(a.z); o.us[3] = f2b(a.w);
    o.us[4] = f2b(b.x); o.us[5] = f2b(b.y); o.us[6] = f2b(b.z); o.us[7] = f2b(b.w);
    ((uint4*)g0)[idx] = o.v;
    return;
  }
  int c = idx - 640000;
  if (c <= N_NODES) {                 // row_start[c] = lower_bound(dst, c)
    int lo = 0, hi = N_EDGES;
    while (lo < hi) {
      int mid = (lo + hi) >> 1;
      if (dst[mid] < c) lo = mid + 1; else hi = mid;
    }
    row_start[c] = lo;
  }
}

// ---------------- batched f32 128x128 products (weight folding) ----------------
struct MMJob {
  const float* A; const float* B;
  float* Cf; unsigned short* Cb;
  float scale;
  int abt; int ncolsB; int storeT; int padrows;
};
struct MMStage { MMJob jobs[4]; int njobs; int bias; };

__global__ __launch_bounds__(256) void mm_stage(
    MMStage st,
    const float* __restrict__ Wq, const float* __restrict__ Wk,
    const float* __restrict__ Wv, const float* __restrict__ Wout,
    const float* __restrict__ bq, const float* __restrict__ bv,
    const float* __restrict__ bout,
    const float* __restrict__ C2, const float* __restrict__ C3,
    float* __restrict__ zb, float* __restrict__ bout2)
{
  int blk = blockIdx.x;
  if (blk < st.njobs * 64) {
    MMJob J = st.jobs[blk >> 6];
    int bi = blk & 63;
    int ty = threadIdx.x >> 7;        // 0..1
    int c  = threadIdx.x & 127;
    int r  = bi * 2 + ty;
    float acc = 0.f;
    if (J.abt) {
      const float* ar = J.A + (size_t)r * 128;
      const float* br = J.B + (size_t)c * 128;
      #pragma unroll 4
      for (int j = 0; j < 128; ++j) acc += ar[j] * br[j];
    } else if (c < J.ncolsB) {
      const float* ar = J.A + (size_t)r * 128;
      #pragma unroll 4
      for (int j = 0; j < 128; ++j) acc += ar[j] * J.B[(size_t)j * J.ncolsB + c];
    }
    acc *= J.scale;
    if (J.storeT) {
      if (c < J.ncolsB) {
        if (J.Cb) J.Cb[(size_t)c * 128 + r] = f2b(acc);
        else      J.Cf[(size_t)c * 128 + r] = acc;
      } else if (c < J.padrows && J.Cb) {
        J.Cb[(size_t)c * 128 + r] = 0;
      }
    } else if (c < J.ncolsB) {
      if (J.Cb) J.Cb[(size_t)r * J.ncolsB + c] = f2b(acc);
      else      J.Cf[(size_t)r * J.ncolsB + c] = acc;
    }
    return;
  }
  if (!st.bias) return;

  // ---- bias block (zeros in this dataset, kept for exactness) ----
  int t = threadIdx.x;
  __shared__ float cb[128], v1[128], v2[128], cbn[128];
  if (t < 128) {
    const float* wk0 = Wk + (size_t)t * 128;
    float s = 0.f;
    for (int o = 0; o < 128; ++o) s += bq[o] * wk0[o];
    zb[t] = s * SCALING;              // zb layer 0 (Cv = I)
    cb[t] = bv[t];                    // cb^{(1)} = bv_0
  }
  __syncthreads();
  for (int l = 1; l < 4; ++l) {
    const float* Cvl = (l == 1) ? Wv : (l == 2 ? C2 : C3);
    if (t < 128) {
      float s = bq[(size_t)l * 128 + t];
      for (int o = 0; o < 128; ++o) s += cb[o] * Wq[(size_t)l * 16384 + (size_t)o * 128 + t];
      v1[t] = s;
    }
    __syncthreads();
    if (t < 128) {
      float s = 0.f;
      const float* wkr = Wk + (size_t)l * 16384 + (size_t)t * 128;
      for (int o = 0; o < 128; ++o) s += v1[o] * wkr[o];
      v2[t] = s;
    }
    __syncthreads();
    if (t < 128) {
      float s = 0.f;
      const float* cvr = Cvl + (size_t)t * 128;
      for (int d = 0; d < 128; ++d) s += v2[d] * cvr[d];
      zb[(size_t)l * 128 + t] = s * SCALING;
      float s2 = bv[(size_t)l * 128 + t];
      for (int d = 0; d < 128; ++d) s2 += cb[d] * Wv[(size_t)l * 16384 + (size_t)d * 128 + t];
      cbn[t] = s2;
    }
    __syncthreads();
    if (t < 128) cb[t] = cbn[t];
    __syncthreads();
  }
  if (t < N_CLASSES) {
    float s = bout[t];
    for (int d = 0; d < 128; ++d) s += cb[d] * Wout[(size_t)d * N_CLASSES + t];
    bout2[t] = s;
  }
}

// ---------------- fused layer: z-GEMM (LDS) + edge softmax-aggregate -----------
// grid 1250 x 256 thr. Block owns 32 dst nodes. Phase 1: z tile via MFMA into
// LDS (z never hits global). Phase 2: each wave does 8 nodes' edge work.
// LAST: also fold the output head (gout stays in LDS, write log_softmax).
template<bool LAST>
__global__ __launch_bounds__(256) void layer_fused(
    const unsigned short* __restrict__ g,      // 40000x128 bf16 (layer input)
    const unsigned short* __restrict__ Wt,     // WZ_l [128][128] bf16 out-major
    const float* __restrict__ bias,            // zb_l [128] f32
    const int* __restrict__ src, const int* __restrict__ row_start,
    unsigned short* __restrict__ gout,         // layer output (unused if LAST)
    const unsigned short* __restrict__ WOt,    // [48][128] bf16 (LAST only)
    const float* __restrict__ bout2,           // [48] f32 (LAST only)
    float* __restrict__ out)                   // 40000x40 f32 (LAST only)
{
  __shared__ __align__(16) unsigned char zs[8192];            // 32x128 bf16 z
  __shared__ __align__(16) unsigned char gs2[LAST ? 8192 : 16]; // gout staging
  __shared__ __align__(16) float os[LAST ? 32 * N_CLASSES : 4]; // logits

  const int tid = threadIdx.x;
  const int wid = tid >> 6, lane = tid & 63;
  const int r = lane & 15, kg = lane >> 4;

  // ---- phase 1: z tile for the block's 32 nodes (gemm_z structure) ----
  {
    const int colhalf = wid & 1, rowsub = wid >> 1;
    const int colbase = colhalf * 64;
    const int ro = rowsub * 16 + r;               // local row 0..31
    const int row = blockIdx.x * 32 + ro;         // < 40000

    short8 hf[4];
    #pragma unroll
    for (int kc = 0; kc < 4; ++kc)
      hf[kc] = *(const short8*)(g + (size_t)row * 128 + kc * 32 + kg * 8);

    floatx4 acc[4];
    #pragma unroll
    for (int df = 0; df < 4; ++df) acc[df] = (floatx4){0.f, 0.f, 0.f, 0.f};

    const unsigned short* wp = Wt + (size_t)(colbase + r) * 128 + kg * 8;
    #pragma unroll
    for (int df = 0; df < 4; ++df) {
      #pragma unroll
      for (int kc = 0; kc < 4; ++kc) {
        short8 wf = *(const short8*)(wp + df * 2048 + kc * 32);
        acc[df] = __builtin_amdgcn_mfma_f32_16x16x32_bf16(wf, hf[kc], acc[df], 0, 0, 0);
      }
    }

    #pragma unroll
    for (int df = 0; df < 4; ++df) {
      float4 b4 = *(const float4*)&bias[colbase + df * 16 + kg * 4];
      union { unsigned short us[4]; uint2 u2; } o;
      o.us[0] = f2b(acc[df][0] + b4.x);
      o.us[1] = f2b(acc[df][1] + b4.y);
      o.us[2] = f2b(acc[df][2] + b4.z);
      o.us[3] = f2b(acc[df][3] + b4.w);
      int colb = (colbase + df * 16 + kg * 4) * 2;
      *(uint2*)(zs + ro * 256 + (colb ^ ((ro & 7) << 4))) = o.u2;
    }
  }
  __syncthreads();

  // ---- phase 2: edge softmax-aggregate, 8 nodes per wave ----
  const int sg = lane >> 4, sl = lane & 15;

#define LOADG(VLD, HF, C, R1)                                           \
  {                                                                     \
    int e_ = (C) + sg;                                                  \
    VLD = e_ < R1;                                                      \
    int s_ = VLD ? src[e_] : 0;                                         \
    HF = *(const short8*)(g + ((size_t)s_ << 7) + sl * 8);              \
  }

#define COMPG(VLD, HF)                                                  \
  {                                                                     \
    float hd_[8];                                                       \
    _Pragma("unroll")                                                   \
    for (int j = 0; j < 8; ++j) hd_[j] = b2f((unsigned short)HF[j]);    \
    float d0_ = 0.f, d1_ = 0.f;                                         \
    _Pragma("unroll")                                                   \
    for (int j = 0; j < 4; ++j) d0_ += qd[j] * hd_[j];                  \
    _Pragma("unroll")                                                   \
    for (int j = 4; j < 8; ++j) d1_ += qd[j] * hd_[j];                  \
    float d_ = d0_ + d1_;                                               \
    d_ += __shfl_xor(d_, 1, 64);                                        \
    d_ += __shfl_xor(d_, 2, 64);                                        \
    d_ += __shfl_xor(d_, 4, 64);                                        \
    d_ += __shfl_xor(d_, 8, 64);                                        \
    float w_ = VLD ? __expf(d_) : 0.f;                                  \
    ws += w_;                                                           \
    _Pragma("unroll")                                                   \
    for (int j = 0; j < 8; ++j) acc[j] += w_ * hd_[j];                  \
  }

  for (int ni = 0; ni < 8; ++ni) {
    const int nl = wid * 8 + ni;                  // local node 0..31
    const int node = blockIdx.x * 32 + nl;

    short8 qf = *(const short8*)(zs + nl * 256 + ((sl * 16) ^ ((nl & 7) << 4)));
    float qd[8];
    #pragma unroll
    for (int j = 0; j < 8; ++j) qd[j] = b2f((unsigned short)qf[j]);

    const int r0 = row_start[node], r1 = row_start[node + 1];

    float acc[8] = {0.f, 0.f, 0.f, 0.f, 0.f, 0.f, 0.f, 0.f};
    float ws = 0.f;

    bool vA, vB;
    short8 hA, hB;
    LOADG(vA, hA, r0, r1);
    LOADG(vB, hB, r0 + 4, r1);

    for (int c = r0; c < r1; c += 8) {
      bool vC, vD;
      short8 hC, hD;
      LOADG(vC, hC, c + 8, r1);
      LOADG(vD, hD, c + 12, r1);
      COMPG(vA, hA);
      COMPG(vB, hB);
      vA = vC; hA = hC;
      vB = vD; hB = hD;
    }

    #pragma unroll
    for (int off = 16; off <= 32; off <<= 1) {
      ws += __shfl_xor(ws, off, 64);
      #pragma unroll
      for (int j = 0; j < 8; ++j) acc[j] += __shfl_xor(acc[j], off, 64);
    }

    if (sg == 0) {
      float inv = (ws > 1e-20f) ? 1.0f / ws : 0.0f;
      union { unsigned short us[8]; uint4 u4; } o;
      #pragma unroll
      for (int j = 0; j < 8; ++j) o.us[j] = f2b(acc[j] * inv);
      if (LAST)
        *(uint4*)(gs2 + nl * 256 + ((sl * 16) ^ ((nl & 7) << 4))) = o.u4;
      else
        *(uint4*)(gout + (size_t)node * 128 + sl * 8) = o.u4;
    }
  }

#undef LOADG
#undef COMPG

  if (!LAST) return;

  // ---- phase 3 (LAST): output head for the block's 32 nodes ----
  __syncthreads();
  if (wid < 2) {
    const int rowl = wid * 16 + r;                // local node 0..31
    floatx4 acc[3];
    #pragma unroll
    for (int n = 0; n < 3; ++n) acc[n] = (floatx4){0.f, 0.f, 0.f, 0.f};

    const unsigned short* bp = WOt + (size_t)r * 128 + kg * 8;
    #pragma unroll
    for (int kc = 0; kc < 4; ++kc) {
      short8 a0 = *(const short8*)(gs2 + rowl * 256 +
                                   ((kc * 64 + kg * 16) ^ ((rowl & 7) << 4)));
      #pragma unroll
      for (int n = 0; n < 3; ++n) {
        short8 b = *(const short8*)(bp + n * 2048 + kc * 32);
        acc[n] = __builtin_amdgcn_mfma_f32_16x16x32_bf16(a0, b, acc[n], 0, 0, 0);
      }
    }

    float bn0 = bout2[r];
    float bn1 = bout2[16 + r];
    float bn2 = (r < 8) ? bout2[32 + r] : 0.f;

    #pragma unroll
    for (int gi = 0; gi < 4; ++gi) {
      int rl = wid * 16 + kg * 4 + gi;            // local node 0..31
      float l0 = acc[0][gi] + bn0;
      float l1 = acc[1][gi] + bn1;
      float l2 = acc[2][gi] + bn2;                // valid only if r < 8
      float m = fmaxf(l0, l1);
      if (r < 8) m = fmaxf(m, l2);
      #pragma unroll
      for (int off = 8; off >= 1; off >>= 1) m = fmaxf(m, __shfl_xor(m, off, 64));
      float s = __expf(l0 - m) + __expf(l1 - m) + ((r < 8) ? __expf(l2 - m) : 0.f);
      #pragma unroll
      for (int off = 8; off >= 1; off >>= 1) s += __shfl_xor(s, off, 64);
      float lse = m + logf(s);
      os[rl * N_CLASSES + r]      = l0 - lse;
      os[rl * N_CLASSES + 16 + r] = l1 - lse;
      if (r < 8) os[rl * N_CLASSES + 32 + r] = l2 - lse;
    }
  }
  __syncthreads();

  // contiguous store: 32 rows x 160B = 5120B (320 uint4)
  float* dstb = out + (size_t)blockIdx.x * 32 * N_CLASSES;
  #pragma unroll
  for (int i = 0; i < 2; ++i) {
    int idx = i * 256 + tid;
    if (idx < 320)
      *(uint4*)(dstb + idx * 4) = *(const uint4*)(os + idx * 4);
  }
}

extern "C" void kernel_launch(void* const* d_in, const int* in_sizes, int n_in,
                              void* d_out, int out_size, void* d_ws, size_t ws_size,
                              hipStream_t stream) {
  const float* h_in = (const float*)d_in[0];
  const int*   src  = (const int*)d_in[1];
  const int*   dst  = (const int*)d_in[2];
  const float* Wq   = (const float*)d_in[3];
  const float* bq   = (const float*)d_in[4];
  const float* Wk   = (const float*)d_in[5];
  const float* bk   = (const float*)d_in[6];  // cancels in softmax (dst-constant)
  const float* Wv   = (const float*)d_in[7];
  const float* bv   = (const float*)d_in[8];
  const float* Wout = (const float*)d_in[9];
  const float* bout = (const float*)d_in[10];
  float* out = (float*)d_out;
  (void)bk;

  char* ws = (char*)d_ws;
  size_t off = 0;
  auto alloc = [&](size_t bytes) -> void* {
    void* p = ws + off;
    off += (bytes + 255) & ~(size_t)255;
    return p;
  };
  int*            row_start = (int*)           alloc((size_t)(N_NODES + 1) * sizeof(int));
  unsigned short* g0        = (unsigned short*)alloc((size_t)N_NODES * 128 * 2);
  unsigned short* g1        = (unsigned short*)alloc((size_t)N_NODES * 128 * 2);
  unsigned short* WZ        = (unsigned short*)alloc((size_t)4 * 16384 * 2);
  unsigned short* WOt       = (unsigned short*)alloc((size_t)48 * 128 * 2);
  float*          C2        = (float*)alloc(16384 * sizeof(float));
  float*          C3        = (float*)alloc(16384 * sizeof(float));
  float*          C4        = (float*)alloc(16384 * sizeof(float));
  float*          Abuf      = (float*)alloc(3 * 16384 * sizeof(float));
  float*          Bbuf      = (float*)alloc(3 * 16384 * sizeof(float));
  float*          zb        = (float*)alloc(4 * 128 * sizeof(float));
  float*          bout2     = (float*)alloc(64 * sizeof(float));

  setup_all<<<(680001 + 255) / 256, 256, 0, stream>>>(h_in, dst, g0, row_start);

  auto J = [](const float* A, const float* B, float* Cf, unsigned short* Cb,
              float scale, int abt, int ncolsB, int storeT, int padrows) {
    MMJob j; j.A = A; j.B = B; j.Cf = Cf; j.Cb = Cb; j.scale = scale;
    j.abt = abt; j.ncolsB = ncolsB; j.storeT = storeT; j.padrows = padrows;
    return j;
  };
  const float* Wq_l[4] = {Wq, Wq + 16384, Wq + 32768, Wq + 49152};
  const float* Wk_l[4] = {Wk, Wk + 16384, Wk + 32768, Wk + 49152};
  const float* Wv_l[4] = {Wv, Wv + 16384, Wv + 32768, Wv + 49152};

  MMStage s0 = {};
  s0.jobs[0] = J(Wk_l[0], Wq_l[0], nullptr, WZ, SCALING, 1, 128, 0, 0);
  s0.jobs[1] = J(Wv_l[0], Wv_l[1], C2, nullptr, 1.f, 0, 128, 0, 0);
  s0.jobs[2] = J(Wv_l[0], Wk_l[1], Abuf, nullptr, 1.f, 0, 128, 0, 0);
  s0.jobs[3] = J(Wv_l[0], Wq_l[1], Bbuf, nullptr, 1.f, 0, 128, 0, 0);
  s0.njobs = 4; s0.bias = 0;

  MMStage s1 = {};
  s1.jobs[0] = J(Abuf, Bbuf, nullptr, WZ + 16384, SCALING, 1, 128, 0, 0);
  s1.jobs[1] = J(C2, Wv_l[2], C3, nullptr, 1.f, 0, 128, 0, 0);
  s1.jobs[2] = J(C2, Wk_l[2], Abuf + 16384, nullptr, 1.f, 0, 128, 0, 0);
  s1.jobs[3] = J(C2, Wq_l[2], Bbuf + 16384, nullptr, 1.f, 0, 128, 0, 0);
  s1.njobs = 4; s1.bias = 0;

  MMStage s2 = {};
  s2.jobs[0] = J(Abuf + 16384, Bbuf + 16384, nullptr, WZ + 32768, SCALING, 1, 128, 0, 0);
  s2.jobs[1] = J(C3, Wv_l[3], C4, nullptr, 1.f, 0, 128, 0, 0);
  s2.jobs[2] = J(C3, Wk_l[3], Abuf + 32768, nullptr, 1.f, 0, 128, 0, 0);
  s2.jobs[3] = J(C3, Wq_l[3], Bbuf + 32768, nullptr, 1.f, 0, 128, 0, 0);
  s2.njobs = 4; s2.bias = 0;

  MMStage s3 = {};
  s3.jobs[0] = J(Abuf + 32768, Bbuf + 32768, nullptr, WZ + 49152, SCALING, 1, 128, 0, 0);
  s3.jobs[1] = J(C4, Wout, nullptr, WOt, 1.f, 0, N_CLASSES, 1, 48);
  s3.njobs = 2; s3.bias = 1;

  mm_stage<<<4 * 64, 256, 0, stream>>>(s0, Wq, Wk, Wv, Wout, bq, bv, bout, C2, C3, zb, bout2);
  mm_stage<<<4 * 64, 256, 0, stream>>>(s1, Wq, Wk, Wv, Wout, bq, bv, bout, C2, C3, zb, bout2);
  mm_stage<<<4 * 64, 256, 0, stream>>>(s2, Wq, Wk, Wv, Wout, bq, bv, bout, C2, C3, zb, bout2);
  mm_stage<<<2 * 64 + 1, 256, 0, stream>>>(s3, Wq, Wk, Wv, Wout, bq, bv, bout, C2, C3, zb, bout2);

  // layers 0..2: fused z-GEMM + edge; layer 3: + folded head
  layer_fused<false><<<1250, 256, 0, stream>>>(
      g0, WZ, zb, src, row_start, g1, nullptr, nullptr, nullptr);
  layer_fused<false><<<1250, 256, 0, stream>>>(
      g1, WZ + 16384, zb + 128, src, row_start, g0, nullptr, nullptr, nullptr);
  layer_fused<false><<<1250, 256, 0, stream>>>(
      g0, WZ + 32768, zb + 256, src, row_start, g1, nullptr, nullptr, nullptr);
  layer_fused<true><<<1250, 256, 0, stream>>>(
      g1, WZ + 49152, zb + 384, src, row_start, nullptr, WOt, bout2, out);
}

// Round 12
// 241.545 us; speedup vs baseline: 1.0554x; 1.0554x over previous
//
#include <hip/hip_runtime.h>
#include <math.h>

#define N_NODES 40000
#define N_EDGES 640000
#define HIDDEN 128
#define N_LAYERS 4
#define N_CLASSES 40
#define SCALING 0.08838834764831845f

typedef __attribute__((ext_vector_type(8))) short short8;
typedef __attribute__((ext_vector_type(4))) float floatx4;

static __device__ __forceinline__ float b2f(unsigned short u) {
  return __uint_as_float(((unsigned)u) << 16);
}
static __device__ __forceinline__ unsigned short f2b(float f) {
  unsigned u = __float_as_uint(f);
  u += 0x7fff + ((u >> 16) & 1);   // round-to-nearest-even
  return (unsigned short)(u >> 16);
}

// ---------------- f32 128x128 product jobs (weight folding) --------------------
// AB form:  out[r][c] = sum_j A[r][j] * B[j*ncolsB + c]
// ABt form: out[r][c] = sum_j A[r][j] * B[c*128 + j]
struct MMJob {
  const float* A; const float* B;
  float* Cf; unsigned short* Cb;
  float scale;
  int abt; int ncolsB; int storeT; int padrows;
};
struct MM7 { MMJob j[7]; };
struct MM3 { MMJob j[3]; };

static __device__ __forceinline__ void run_job(const MMJob J, int bi) {
  int ty = threadIdx.x >> 7;        // 0..1
  int c  = threadIdx.x & 127;
  int r  = bi * 2 + ty;
  float acc = 0.f;
  if (J.abt) {
    const float* ar = J.A + (size_t)r * 128;
    const float* br = J.B + (size_t)c * 128;
    #pragma unroll 4
    for (int j = 0; j < 128; ++j) acc += ar[j] * br[j];
  } else if (c < J.ncolsB) {
    const float* ar = J.A + (size_t)r * 128;
    #pragma unroll 4
    for (int j = 0; j < 128; ++j) acc += ar[j] * J.B[(size_t)j * J.ncolsB + c];
  }
  acc *= J.scale;
  if (J.storeT) {
    if (c < J.ncolsB) {
      if (J.Cb) J.Cb[(size_t)c * 128 + r] = f2b(acc);
      else      J.Cf[(size_t)c * 128 + r] = acc;
    } else if (c < J.padrows && J.Cb) {
      J.Cb[(size_t)c * 128 + r] = 0;
    }
  } else if (c < J.ncolsB) {
    if (J.Cb) J.Cb[(size_t)r * J.ncolsB + c] = f2b(acc);
    else      J.Cf[(size_t)r * J.ncolsB + c] = acc;
  }
}

// ---------------- K1: setup (cast h0, CSR) + fold stage 1 + zb0 ----------------
// blocks [0,2657): setup; [2657,3105): 7 jobs x 64; 3105: zb layer 0.
__global__ __launch_bounds__(256) void setup_fold1(
    const float* __restrict__ h_in, const int* __restrict__ dst,
    const float* __restrict__ bq, const float* __restrict__ Wk,
    unsigned short* __restrict__ g0, int* __restrict__ row_start,
    float* __restrict__ zb, MM7 st)
{
  int blk = blockIdx.x;
  if (blk < 2657) {
    int idx = blk * 256 + threadIdx.x;
    if (idx < 640000) {
      const float4* p = (const float4*)h_in + (size_t)idx * 2;
      float4 a = p[0], b = p[1];
      union { unsigned short us[8]; uint4 v; } o;
      o.us[0] = f2b(a.x); o.us[1] = f2b(a.y); o.us[2] = f2b(a.z); o.us[3] = f2b(a.w);
      o.us[4] = f2b(b.x); o.us[5] = f2b(b.y); o.us[6] = f2b(b.z); o.us[7] = f2b(b.w);
      ((uint4*)g0)[idx] = o.v;
      return;
    }
    int c = idx - 640000;
    if (c <= N_NODES) {
      int lo = 0, hi = N_EDGES;
      while (lo < hi) {
        int mid = (lo + hi) >> 1;
        if (dst[mid] < c) lo = mid + 1; else hi = mid;
      }
      row_start[c] = lo;
    }
    return;
  }
  if (blk < 3105) {
    int b2 = blk - 2657;
    run_job(st.j[b2 >> 6], b2 & 63);
    return;
  }
  // zb layer 0: zb[t] = S * sum_o bq0[o] * Wk0[t][o]
  int t = threadIdx.x;
  if (t < 128) {
    const float* wkr = Wk + (size_t)t * 128;
    float s = 0.f;
    #pragma unroll 4
    for (int o = 0; o < 128; ++o) s += bq[o] * wkr[o];
    zb[t] = s * SCALING;
  }
}

// ---------------- K2: fold stage 2 (7 jobs x 64 blocks) ------------------------
__global__ __launch_bounds__(256) void fold2(MM7 st) {
  run_job(st.j[blockIdx.x >> 6], blockIdx.x & 63);
}

// ---------------- K3: fold stage 3 + bias chain + gemm_z layer 0 ---------------
// blocks [0,192): 3 jobs; 192: bias chain (zb1..3, bout2); [193,1443): z0 tiles.
__global__ __launch_bounds__(256) void fold3_z0(
    MM3 st,
    const float* __restrict__ Wq, const float* __restrict__ Wk,
    const float* __restrict__ Wv, const float* __restrict__ Wout,
    const float* __restrict__ bq, const float* __restrict__ bv,
    const float* __restrict__ bout,
    const float* __restrict__ D01, const float* __restrict__ C3f,
    float* __restrict__ zb, float* __restrict__ bout2,
    const unsigned short* __restrict__ g, const unsigned short* __restrict__ WZ0,
    unsigned short* __restrict__ zout)
{
  int blk = blockIdx.x;
  if (blk < 192) {
    run_job(st.j[blk >> 6], blk & 63);
    return;
  }
  if (blk == 192) {
    // bias chain: zb for layers 1..3, bout2. (All-zero in this dataset.)
    int t = threadIdx.x;
    __shared__ float cb[128], v1[128], v2[128], cbn[128];
    if (t < 128) cb[t] = bv[t];
    __syncthreads();
    for (int l = 1; l < 4; ++l) {
      const float* Cvl = (l == 1) ? Wv : (l == 2 ? D01 : C3f);
      if (t < 128) {
        float s = bq[(size_t)l * 128 + t];
        for (int o = 0; o < 128; ++o) s += cb[o] * Wq[(size_t)l * 16384 + (size_t)o * 128 + t];
        v1[t] = s;
      }
      __syncthreads();
      if (t < 128) {
        float s = 0.f;
        const float* wkr = Wk + (size_t)l * 16384 + (size_t)t * 128;
        for (int o = 0; o < 128; ++o) s += v1[o] * wkr[o];
        v2[t] = s;
      }
      __syncthreads();
      if (t < 128) {
        float s = 0.f;
        const float* cvr = Cvl + (size_t)t * 128;
        for (int d = 0; d < 128; ++d) s += v2[d] * cvr[d];
        zb[(size_t)l * 128 + t] = s * SCALING;
        float s2 = bv[(size_t)l * 128 + t];
        for (int d = 0; d < 128; ++d) s2 += cb[d] * Wv[(size_t)l * 16384 + (size_t)d * 128 + t];
        cbn[t] = s2;
      }
      __syncthreads();
      if (t < 128) cb[t] = cbn[t];
      __syncthreads();
    }
    if (t < N_CLASSES) {
      float s = bout[t];
      for (int d = 0; d < 128; ++d) s += cb[d] * Wout[(size_t)d * N_CLASSES + t];
      bout2[t] = s;
    }
    return;
  }

  // ---- gemm_z for layer 0 (reads zb[0..127] written in K1 — no race) ----
  {
    const int tile = blk - 193;                 // 0..1249
    constexpr int ROWB = 256;
    __shared__ __align__(16) unsigned char cs[32 * ROWB];

    const int tid = threadIdx.x;
    const int wid = tid >> 6, lane = tid & 63;
    const int r = lane & 15, kg = lane >> 4;
    const int colhalf = wid & 1, rowsub = wid >> 1;
    const int colbase = colhalf * 64;
    const int ro = rowsub * 16 + r;
    const int row = tile * 32 + ro;

    short8 hf[4];
    #pragma unroll
    for (int kc = 0; kc < 4; ++kc)
      hf[kc] = *(const short8*)(g + (size_t)row * 128 + kc * 32 + kg * 8);

    floatx4 acc[4];
    #pragma unroll
    for (int df = 0; df < 4; ++df) acc[df] = (floatx4){0.f, 0.f, 0.f, 0.f};

    const unsigned short* wp = WZ0 + (size_t)(colbase + r) * 128 + kg * 8;
    #pragma unroll
    for (int df = 0; df < 4; ++df) {
      #pragma unroll
      for (int kc = 0; kc < 4; ++kc) {
        short8 wf = *(const short8*)(wp + df * 2048 + kc * 32);
        acc[df] = __builtin_amdgcn_mfma_f32_16x16x32_bf16(wf, hf[kc], acc[df], 0, 0, 0);
      }
    }

    #pragma unroll
    for (int df = 0; df < 4; ++df) {
      float4 b4 = *(const float4*)&zb[colbase + df * 16 + kg * 4];
      union { unsigned short us[4]; uint2 u2; } o;
      o.us[0] = f2b(acc[df][0] + b4.x);
      o.us[1] = f2b(acc[df][1] + b4.y);
      o.us[2] = f2b(acc[df][2] + b4.z);
      o.us[3] = f2b(acc[df][3] + b4.w);
      int colb = (colbase + df * 16 + kg * 4) * 2;
      *(uint2*)(cs + ro * ROWB + (colb ^ ((ro & 7) << 4))) = o.u2;
    }
    __syncthreads();

    unsigned char* dstb = (unsigned char*)(zout + (size_t)tile * 32 * 128);
    #pragma unroll
    for (int i = 0; i < 2; ++i) {
      int byte = (i * 256 + tid) * 16;
      int ro2 = byte / ROWB;
      int colb2 = byte & (ROWB - 1);
      *(uint4*)(dstb + byte) =
          *(const uint4*)(cs + ro2 * ROWB + (colb2 ^ ((ro2 & 7) << 4)));
    }
  }
}

// ---------------- node GEMM via MFMA bf16, LDS-staged coalesced epilogue -------
__global__ __launch_bounds__(256) void gemm_z(
    const unsigned short* __restrict__ A,
    const unsigned short* __restrict__ Wt,
    const float* __restrict__ bias,
    unsigned short* __restrict__ C)
{
  constexpr int ROWB = 256;
  __shared__ __align__(16) unsigned char cs[32 * ROWB];

  const int tid = threadIdx.x;
  const int wid = tid >> 6, lane = tid & 63;
  const int r = lane & 15, kg = lane >> 4;
  const int colhalf = wid & 1, rowsub = wid >> 1;
  const int colbase = colhalf * 64;
  const int ro = rowsub * 16 + r;
  const int row = blockIdx.x * 32 + ro;

  short8 hf[4];
  #pragma unroll
  for (int kc = 0; kc < 4; ++kc)
    hf[kc] = *(const short8*)(A + (size_t)row * 128 + kc * 32 + kg * 8);

  floatx4 acc[4];
  #pragma unroll
  for (int df = 0; df < 4; ++df) acc[df] = (floatx4){0.f, 0.f, 0.f, 0.f};

  const unsigned short* wp = Wt + (size_t)(colbase + r) * 128 + kg * 8;
  #pragma unroll
  for (int df = 0; df < 4; ++df) {
    #pragma unroll
    for (int kc = 0; kc < 4; ++kc) {
      short8 wf = *(const short8*)(wp + df * 2048 + kc * 32);
      acc[df] = __builtin_amdgcn_mfma_f32_16x16x32_bf16(wf, hf[kc], acc[df], 0, 0, 0);
    }
  }

  #pragma unroll
  for (int df = 0; df < 4; ++df) {
    float4 b4 = *(const float4*)&bias[colbase + df * 16 + kg * 4];
    union { unsigned short us[4]; uint2 u2; } o;
    o.us[0] = f2b(acc[df][0] + b4.x);
    o.us[1] = f2b(acc[df][1] + b4.y);
    o.us[2] = f2b(acc[df][2] + b4.z);
    o.us[3] = f2b(acc[df][3] + b4.w);
    int colb = (colbase + df * 16 + kg * 4) * 2;
    *(uint2*)(cs + ro * ROWB + (colb ^ ((ro & 7) << 4))) = o.u2;
  }
  __syncthreads();

  unsigned char* dstb = (unsigned char*)(C + (size_t)blockIdx.x * 32 * 128);
  #pragma unroll
  for (int i = 0; i < 2; ++i) {
    int byte = (i * 256 + tid) * 16;
    int ro2 = byte / ROWB;
    int colb2 = byte & (ROWB - 1);
    *(uint4*)(dstb + byte) =
        *(const uint4*)(cs + ro2 * ROWB + (colb2 ^ ((ro2 & 7) << 4)));
  }
}

// shared edge-phase macros (1 node/wave, depth-2 pipeline, R10-proven)
#define EDGE_LOADG(VLD, HF, C)                                          \
  {                                                                     \
    int e_ = (C) + sg;                                                  \
    VLD = e_ < r1;                                                      \
    int s_ = VLD ? src[e_] : 0;                                         \
    HF = *(const short8*)(g + ((size_t)s_ << 7) + sl * 8);              \
  }

#define EDGE_COMPG(VLD, HF)                                             \
  {                                                                     \
    float hd_[8];                                                       \
    _Pragma("unroll")                                                   \
    for (int j = 0; j < 8; ++j) hd_[j] = b2f((unsigned short)HF[j]);    \
    float d0_ = 0.f, d1_ = 0.f;                                         \
    _Pragma("unroll")                                                   \
    for (int j = 0; j < 4; ++j) d0_ += qd[j] * hd_[j];                  \
    _Pragma("unroll")                                                   \
    for (int j = 4; j < 8; ++j) d1_ += qd[j] * hd_[j];                  \
    float d_ = d0_ + d1_;                                               \
    d_ += __shfl_xor(d_, 1, 64);                                        \
    d_ += __shfl_xor(d_, 2, 64);                                        \
    d_ += __shfl_xor(d_, 4, 64);                                        \
    d_ += __shfl_xor(d_, 8, 64);                                        \
    float w_ = VLD ? __expf(d_) : 0.f;                                  \
    ws += w_;                                                           \
    _Pragma("unroll")                                                   \
    for (int j = 0; j < 8; ++j) acc[j] += w_ * hd_[j];                  \
  }

#define EDGE_BODY                                                       \
  float acc[8] = {0.f, 0.f, 0.f, 0.f, 0.f, 0.f, 0.f, 0.f};              \
  float ws = 0.f;                                                       \
  bool vA, vB;                                                          \
  short8 hA, hB;                                                        \
  EDGE_LOADG(vA, hA, r0);                                               \
  EDGE_LOADG(vB, hB, r0 + 4);                                           \
  for (int c = r0; c < r1; c += 8) {                                    \
    bool vC, vD;                                                        \
    short8 hC, hD;                                                      \
    EDGE_LOADG(vC, hC, c + 8);                                          \
    EDGE_LOADG(vD, hD, c + 12);                                         \
    EDGE_COMPG(vA, hA);                                                 \
    EDGE_COMPG(vB, hB);                                                 \
    vA = vC; hA = hC;                                                   \
    vB = vD; hB = hD;                                                   \
  }                                                                     \
  _Pragma("unroll")                                                     \
  for (int off = 16; off <= 32; off <<= 1) {                            \
    ws += __shfl_xor(ws, off, 64);                                      \
    _Pragma("unroll")                                                   \
    for (int j = 0; j < 8; ++j) acc[j] += __shfl_xor(acc[j], off, 64);  \
  }

// ---------------- fused edge attention (layers 0..2) ---------------------------
__global__ __launch_bounds__(128) void edge_fused(
    const unsigned short* __restrict__ z, const unsigned short* __restrict__ g,
    const int* __restrict__ src, const int* __restrict__ row_start,
    unsigned short* __restrict__ gout)
{
  const int lane = threadIdx.x & 63;
  const int node = blockIdx.x * 2 + (threadIdx.x >> 6);
  const int sg = lane >> 4, sl = lane & 15;

  short8 qf = *(const short8*)(z + ((size_t)node << 7) + sl * 8);
  float qd[8];
  #pragma unroll
  for (int j = 0; j < 8; ++j) qd[j] = b2f((unsigned short)qf[j]);

  const int r0 = row_start[node], r1 = row_start[node + 1];

  EDGE_BODY

  if (sg == 0) {
    float inv = (ws > 1e-20f) ? 1.0f / ws : 0.0f;
    union { unsigned short us[8]; uint4 u4; } o;
    #pragma unroll
    for (int j = 0; j < 8; ++j) o.us[j] = f2b(acc[j] * inv);
    *(uint4*)(gout + (size_t)node * 128 + sl * 8) = o.u4;
  }
}

// ---------------- layer 3: edge + folded output head ---------------------------
// After combine, ALL 64 lanes hold the full aggregated row (dims sl*8..sl*8+8).
// Subgroup sg computes classes sg*10+it (it=0..9); lane-reduced log_softmax.
__global__ __launch_bounds__(128) void edge_head(
    const unsigned short* __restrict__ z, const unsigned short* __restrict__ g,
    const int* __restrict__ src, const int* __restrict__ row_start,
    const unsigned short* __restrict__ WOt, const float* __restrict__ bout2,
    float* __restrict__ out)
{
  const int lane = threadIdx.x & 63;
  const int node = blockIdx.x * 2 + (threadIdx.x >> 6);
  const int sg = lane >> 4, sl = lane & 15;

  short8 qf = *(const short8*)(z + ((size_t)node << 7) + sl * 8);
  float qd[8];
  #pragma unroll
  for (int j = 0; j < 8; ++j) qd[j] = b2f((unsigned short)qf[j]);

  const int r0 = row_start[node], r1 = row_start[node + 1];

  EDGE_BODY

  float inv = (ws > 1e-20f) ? 1.0f / ws : 0.0f;

  // head: 40 logits, 4 subgroups x 10 classes
  float cls[10];
  #pragma unroll
  for (int it = 0; it < 10; ++it) {
    int c = sg * 10 + it;
    short8 w = *(const short8*)(WOt + (size_t)c * 128 + sl * 8);
    float p = 0.f;
    #pragma unroll
    for (int j = 0; j < 8; ++j) p += acc[j] * b2f((unsigned short)w[j]);
    p += __shfl_xor(p, 1, 64);
    p += __shfl_xor(p, 2, 64);
    p += __shfl_xor(p, 4, 64);
    p += __shfl_xor(p, 8, 64);
    cls[it] = p * inv + bout2[c];
  }
  float m = cls[0];
  #pragma unroll
  for (int it = 1; it < 10; ++it) m = fmaxf(m, cls[it]);
  m = fmaxf(m, __shfl_xor(m, 16, 64));
  m = fmaxf(m, __shfl_xor(m, 32, 64));
  float s = 0.f;
  #pragma unroll
  for (int it = 0; it < 10; ++it) s += __expf(cls[it] - m);
  s += __shfl_xor(s, 16, 64);
  s += __shfl_xor(s, 32, 64);
  float lse = m + logf(s);

  if (sl < 10) {
    float v = cls[0];
    #pragma unroll
    for (int it = 1; it < 10; ++it) if (sl == it) v = cls[it];
    out[(size_t)node * N_CLASSES + sg * 10 + sl] = v - lse;
  }
}

#undef EDGE_BODY
#undef EDGE_COMPG
#undef EDGE_LOADG

extern "C" void kernel_launch(void* const* d_in, const int* in_sizes, int n_in,
                              void* d_out, int out_size, void* d_ws, size_t ws_size,
                              hipStream_t stream) {
  const float* h_in = (const float*)d_in[0];
  const int*   src  = (const int*)d_in[1];
  const int*   dst  = (const int*)d_in[2];
  const float* Wq   = (const float*)d_in[3];
  const float* bq   = (const float*)d_in[4];
  const float* Wk   = (const float*)d_in[5];
  const float* bk   = (const float*)d_in[6];  // cancels in softmax (dst-constant)
  const float* Wv   = (const float*)d_in[7];
  const float* bv   = (const float*)d_in[8];
  const float* Wout = (const float*)d_in[9];
  const float* bout = (const float*)d_in[10];
  float* out = (float*)d_out;
  (void)bk;

  char* ws = (char*)d_ws;
  size_t off = 0;
  auto alloc = [&](size_t bytes) -> void* {
    void* p = ws + off;
    off += (bytes + 255) & ~(size_t)255;
    return p;
  };
  int*            row_start = (int*)           alloc((size_t)(N_NODES + 1) * sizeof(int));
  unsigned short* g0        = (unsigned short*)alloc((size_t)N_NODES * 128 * 2);
  unsigned short* g1        = (unsigned short*)alloc((size_t)N_NODES * 128 * 2);
  unsigned short* zbuf      = (unsigned short*)alloc((size_t)N_NODES * 128 * 2);
  unsigned short* WZ        = (unsigned short*)alloc((size_t)4 * 16384 * 2);
  unsigned short* WOt       = (unsigned short*)alloc((size_t)48 * 128 * 2);
  float*          D01  = (float*)alloc(16384 * 4);
  float*          D23  = (float*)alloc(16384 * 4);
  float*          A1f  = (float*)alloc(16384 * 4);
  float*          B1f  = (float*)alloc(16384 * 4);
  float*          E3   = (float*)alloc(16384 * 4);
  float*          F3   = (float*)alloc(16384 * 4);
  float*          A2f  = (float*)alloc(16384 * 4);
  float*          B2f  = (float*)alloc(16384 * 4);
  float*          A3f  = (float*)alloc(16384 * 4);
  float*          B3f  = (float*)alloc(16384 * 4);
  float*          C4f  = (float*)alloc(16384 * 4);
  float*          C3f  = (float*)alloc(16384 * 4);
  float*          zb   = (float*)alloc(4 * 128 * 4);
  float*          bout2 = (float*)alloc(64 * 4);

  auto J = [](const float* A, const float* B, float* Cf, unsigned short* Cb,
              float scale, int abt, int ncolsB, int storeT, int padrows) {
    MMJob j; j.A = A; j.B = B; j.Cf = Cf; j.Cb = Cb; j.scale = scale;
    j.abt = abt; j.ncolsB = ncolsB; j.storeT = storeT; j.padrows = padrows;
    return j;
  };
  const float* Wq_l[4] = {Wq, Wq + 16384, Wq + 32768, Wq + 49152};
  const float* Wk_l[4] = {Wk, Wk + 16384, Wk + 32768, Wk + 49152};
  const float* Wv_l[4] = {Wv, Wv + 16384, Wv + 32768, Wv + 49152};

  // stage 1: raw-input products
  MM7 s1;
  s1.j[0] = J(Wk_l[0], Wq_l[0], nullptr, WZ, SCALING, 1, 128, 0, 0);  // WZ0
  s1.j[1] = J(Wv_l[0], Wv_l[1], D01, nullptr, 1.f, 0, 128, 0, 0);
  s1.j[2] = J(Wv_l[2], Wv_l[3], D23, nullptr, 1.f, 0, 128, 0, 0);
  s1.j[3] = J(Wv_l[0], Wk_l[1], A1f, nullptr, 1.f, 0, 128, 0, 0);
  s1.j[4] = J(Wv_l[0], Wq_l[1], B1f, nullptr, 1.f, 0, 128, 0, 0);
  s1.j[5] = J(Wv_l[2], Wk_l[3], E3,  nullptr, 1.f, 0, 128, 0, 0);
  s1.j[6] = J(Wv_l[2], Wq_l[3], F3,  nullptr, 1.f, 0, 128, 0, 0);

  // stage 2
  MM7 s2;
  s2.j[0] = J(A1f, B1f, nullptr, WZ + 16384, SCALING, 1, 128, 0, 0);  // WZ1
  s2.j[1] = J(D01, Wk_l[2], A2f, nullptr, 1.f, 0, 128, 0, 0);
  s2.j[2] = J(D01, Wq_l[2], B2f, nullptr, 1.f, 0, 128, 0, 0);
  s2.j[3] = J(D01, E3, A3f, nullptr, 1.f, 0, 128, 0, 0);
  s2.j[4] = J(D01, F3, B3f, nullptr, 1.f, 0, 128, 0, 0);
  s2.j[5] = J(D01, D23, C4f, nullptr, 1.f, 0, 128, 0, 0);
  s2.j[6] = J(D01, Wv_l[2], C3f, nullptr, 1.f, 0, 128, 0, 0);

  // stage 3
  MM3 s3;
  s3.j[0] = J(A2f, B2f, nullptr, WZ + 32768, SCALING, 1, 128, 0, 0);  // WZ2
  s3.j[1] = J(A3f, B3f, nullptr, WZ + 49152, SCALING, 1, 128, 0, 0);  // WZ3
  s3.j[2] = J(C4f, Wout, nullptr, WOt, 1.f, 0, N_CLASSES, 1, 48);     // WOt

  setup_fold1<<<3106, 256, 0, stream>>>(h_in, dst, bq, Wk, g0, row_start, zb, s1);
  fold2<<<448, 256, 0, stream>>>(s2);
  fold3_z0<<<1443, 256, 0, stream>>>(s3, Wq, Wk, Wv, Wout, bq, bv, bout,
                                     D01, C3f, zb, bout2, g0, WZ, zbuf);

  // layer 0
  edge_fused<<<N_NODES / 2, 128, 0, stream>>>(zbuf, g0, src, row_start, g1);
  // layer 1
  gemm_z<<<1250, 256, 0, stream>>>(g1, WZ + 16384, zb + 128, zbuf);
  edge_fused<<<N_NODES / 2, 128, 0, stream>>>(zbuf, g1, src, row_start, g0);
  // layer 2
  gemm_z<<<1250, 256, 0, stream>>>(g0, WZ + 32768, zb + 256, zbuf);
  edge_fused<<<N_NODES / 2, 128, 0, stream>>>(zbuf, g0, src, row_start, g1);
  // layer 3 + head
  gemm_z<<<1250, 256, 0, stream>>>(g1, WZ + 49152, zb + 384, zbuf);
  edge_head<<<N_NODES / 2, 128, 0, stream>>>(zbuf, g1, src, row_start, WOt, bout2, out);
}

// Round 13
// 238.569 us; speedup vs baseline: 1.0686x; 1.0125x over previous
//
#include <hip/hip_runtime.h>
#include <math.h>

#define N_NODES 40000
#define N_EDGES 640000
#define HIDDEN 128
#define N_LAYERS 4
#define N_CLASSES 40
#define SCALING 0.08838834764831845f
#define LOG2E 1.4426950408889634f

typedef __attribute__((ext_vector_type(8))) short short8;
typedef __attribute__((ext_vector_type(4))) float floatx4;

static __device__ __forceinline__ float b2f(unsigned short u) {
  return __uint_as_float(((unsigned)u) << 16);
}
static __device__ __forceinline__ unsigned short f2b(float f) {
  unsigned u = __float_as_uint(f);
  u += 0x7fff + ((u >> 16) & 1);   // round-to-nearest-even
  return (unsigned short)(u >> 16);
}

// ---------------- f32 128x128 product jobs (weight folding) --------------------
struct MMJob {
  const float* A; const float* B;
  float* Cf; unsigned short* Cb;
  float scale;
  int abt; int ncolsB; int storeT; int padrows;
};
struct MM7 { MMJob j[7]; };
struct MM3 { MMJob j[3]; };

static __device__ __forceinline__ void run_job(const MMJob J, int bi) {
  int ty = threadIdx.x >> 7;        // 0..1
  int c  = threadIdx.x & 127;
  int r  = bi * 2 + ty;
  float acc = 0.f;
  if (J.abt) {
    const float* ar = J.A + (size_t)r * 128;
    const float* br = J.B + (size_t)c * 128;
    #pragma unroll 4
    for (int j = 0; j < 128; ++j) acc += ar[j] * br[j];
  } else if (c < J.ncolsB) {
    const float* ar = J.A + (size_t)r * 128;
    #pragma unroll 4
    for (int j = 0; j < 128; ++j) acc += ar[j] * J.B[(size_t)j * J.ncolsB + c];
  }
  acc *= J.scale;
  if (J.storeT) {
    if (c < J.ncolsB) {
      if (J.Cb) J.Cb[(size_t)c * 128 + r] = f2b(acc);
      else      J.Cf[(size_t)c * 128 + r] = acc;
    } else if (c < J.padrows && J.Cb) {
      J.Cb[(size_t)c * 128 + r] = 0;
    }
  } else if (c < J.ncolsB) {
    if (J.Cb) J.Cb[(size_t)r * J.ncolsB + c] = f2b(acc);
    else      J.Cf[(size_t)r * J.ncolsB + c] = acc;
  }
}

// ---------------- K1: setup (cast h0, CSR) + fold stage 1 + zb0 ----------------
__global__ __launch_bounds__(256) void setup_fold1(
    const float* __restrict__ h_in, const int* __restrict__ dst,
    const float* __restrict__ bq, const float* __restrict__ Wk,
    unsigned short* __restrict__ g0, int* __restrict__ row_start,
    float* __restrict__ zb, MM7 st)
{
  int blk = blockIdx.x;
  if (blk < 2657) {
    int idx = blk * 256 + threadIdx.x;
    if (idx < 640000) {
      const float4* p = (const float4*)h_in + (size_t)idx * 2;
      float4 a = p[0], b = p[1];
      union { unsigned short us[8]; uint4 v; } o;
      o.us[0] = f2b(a.x); o.us[1] = f2b(a.y); o.us[2] = f2b(a.z); o.us[3] = f2b(a.w);
      o.us[4] = f2b(b.x); o.us[5] = f2b(b.y); o.us[6] = f2b(b.z); o.us[7] = f2b(b.w);
      ((uint4*)g0)[idx] = o.v;
      return;
    }
    int c = idx - 640000;
    if (c <= N_NODES) {
      int lo = 0, hi = N_EDGES;
      while (lo < hi) {
        int mid = (lo + hi) >> 1;
        if (dst[mid] < c) lo = mid + 1; else hi = mid;
      }
      row_start[c] = lo;
    }
    return;
  }
  if (blk < 3105) {
    int b2 = blk - 2657;
    run_job(st.j[b2 >> 6], b2 & 63);
    return;
  }
  // zb layer 0 (exp2-prescaled)
  int t = threadIdx.x;
  if (t < 128) {
    const float* wkr = Wk + (size_t)t * 128;
    float s = 0.f;
    #pragma unroll 4
    for (int o = 0; o < 128; ++o) s += bq[o] * wkr[o];
    zb[t] = s * (SCALING * LOG2E);
  }
}

// ---------------- K2: fold stage 2 (7 jobs x 64 blocks) ------------------------
__global__ __launch_bounds__(256) void fold2(MM7 st) {
  run_job(st.j[blockIdx.x >> 6], blockIdx.x & 63);
}

// ---------------- K3: fold stage 3 + bias chain + gemm_z layer 0 ---------------
__global__ __launch_bounds__(256) void fold3_z0(
    MM3 st,
    const float* __restrict__ Wq, const float* __restrict__ Wk,
    const float* __restrict__ Wv, const float* __restrict__ Wout,
    const float* __restrict__ bq, const float* __restrict__ bv,
    const float* __restrict__ bout,
    const float* __restrict__ D01, const float* __restrict__ C3f,
    float* __restrict__ zb, float* __restrict__ bout2,
    const unsigned short* __restrict__ g, const unsigned short* __restrict__ WZ0,
    unsigned short* __restrict__ zout)
{
  int blk = blockIdx.x;
  if (blk < 192) {
    run_job(st.j[blk >> 6], blk & 63);
    return;
  }
  if (blk == 192) {
    // bias chain: zb for layers 1..3 (exp2-prescaled), bout2.
    int t = threadIdx.x;
    __shared__ float cb[128], v1[128], v2[128], cbn[128];
    if (t < 128) cb[t] = bv[t];
    __syncthreads();
    for (int l = 1; l < 4; ++l) {
      const float* Cvl = (l == 1) ? Wv : (l == 2 ? D01 : C3f);
      if (t < 128) {
        float s = bq[(size_t)l * 128 + t];
        for (int o = 0; o < 128; ++o) s += cb[o] * Wq[(size_t)l * 16384 + (size_t)o * 128 + t];
        v1[t] = s;
      }
      __syncthreads();
      if (t < 128) {
        float s = 0.f;
        const float* wkr = Wk + (size_t)l * 16384 + (size_t)t * 128;
        for (int o = 0; o < 128; ++o) s += v1[o] * wkr[o];
        v2[t] = s;
      }
      __syncthreads();
      if (t < 128) {
        float s = 0.f;
        const float* cvr = Cvl + (size_t)t * 128;
        for (int d = 0; d < 128; ++d) s += v2[d] * cvr[d];
        zb[(size_t)l * 128 + t] = s * (SCALING * LOG2E);
        float s2 = bv[(size_t)l * 128 + t];
        for (int d = 0; d < 128; ++d) s2 += cb[d] * Wv[(size_t)l * 16384 + (size_t)d * 128 + t];
        cbn[t] = s2;
      }
      __syncthreads();
      if (t < 128) cb[t] = cbn[t];
      __syncthreads();
    }
    if (t < N_CLASSES) {
      float s = bout[t];
      for (int d = 0; d < 128; ++d) s += cb[d] * Wout[(size_t)d * N_CLASSES + t];
      bout2[t] = s;
    }
    return;
  }

  // ---- gemm_z for layer 0 ----
  {
    const int tile = blk - 193;                 // 0..1249
    constexpr int ROWB = 256;
    __shared__ __align__(16) unsigned char cs[32 * ROWB];

    const int tid = threadIdx.x;
    const int wid = tid >> 6, lane = tid & 63;
    const int r = lane & 15, kg = lane >> 4;
    const int colhalf = wid & 1, rowsub = wid >> 1;
    const int colbase = colhalf * 64;
    const int ro = rowsub * 16 + r;
    const int row = tile * 32 + ro;

    short8 hf[4];
    #pragma unroll
    for (int kc = 0; kc < 4; ++kc)
      hf[kc] = *(const short8*)(g + (size_t)row * 128 + kc * 32 + kg * 8);

    floatx4 acc[4];
    #pragma unroll
    for (int df = 0; df < 4; ++df) acc[df] = (floatx4){0.f, 0.f, 0.f, 0.f};

    const unsigned short* wp = WZ0 + (size_t)(colbase + r) * 128 + kg * 8;
    #pragma unroll
    for (int df = 0; df < 4; ++df) {
      #pragma unroll
      for (int kc = 0; kc < 4; ++kc) {
        short8 wf = *(const short8*)(wp + df * 2048 + kc * 32);
        acc[df] = __builtin_amdgcn_mfma_f32_16x16x32_bf16(wf, hf[kc], acc[df], 0, 0, 0);
      }
    }

    #pragma unroll
    for (int df = 0; df < 4; ++df) {
      float4 b4 = *(const float4*)&zb[colbase + df * 16 + kg * 4];
      union { unsigned short us[4]; uint2 u2; } o;
      o.us[0] = f2b(acc[df][0] + b4.x);
      o.us[1] = f2b(acc[df][1] + b4.y);
      o.us[2] = f2b(acc[df][2] + b4.z);
      o.us[3] = f2b(acc[df][3] + b4.w);
      int colb = (colbase + df * 16 + kg * 4) * 2;
      *(uint2*)(cs + ro * ROWB + (colb ^ ((ro & 7) << 4))) = o.u2;
    }
    __syncthreads();

    unsigned char* dstb = (unsigned char*)(zout + (size_t)tile * 32 * 128);
    #pragma unroll
    for (int i = 0; i < 2; ++i) {
      int byte = (i * 256 + tid) * 16;
      int ro2 = byte / ROWB;
      int colb2 = byte & (ROWB - 1);
      *(uint4*)(dstb + byte) =
          *(const uint4*)(cs + ro2 * ROWB + (colb2 ^ ((ro2 & 7) << 4)));
    }
  }
}

// ---------------- node GEMM via MFMA bf16, LDS-staged coalesced epilogue -------
__global__ __launch_bounds__(256) void gemm_z(
    const unsigned short* __restrict__ A,
    const unsigned short* __restrict__ Wt,
    const float* __restrict__ bias,
    unsigned short* __restrict__ C)
{
  constexpr int ROWB = 256;
  __shared__ __align__(16) unsigned char cs[32 * ROWB];

  const int tid = threadIdx.x;
  const int wid = tid >> 6, lane = tid & 63;
  const int r = lane & 15, kg = lane >> 4;
  const int colhalf = wid & 1, rowsub = wid >> 1;
  const int colbase = colhalf * 64;
  const int ro = rowsub * 16 + r;
  const int row = blockIdx.x * 32 + ro;

  short8 hf[4];
  #pragma unroll
  for (int kc = 0; kc < 4; ++kc)
    hf[kc] = *(const short8*)(A + (size_t)row * 128 + kc * 32 + kg * 8);

  floatx4 acc[4];
  #pragma unroll
  for (int df = 0; df < 4; ++df) acc[df] = (floatx4){0.f, 0.f, 0.f, 0.f};

  const unsigned short* wp = Wt + (size_t)(colbase + r) * 128 + kg * 8;
  #pragma unroll
  for (int df = 0; df < 4; ++df) {
    #pragma unroll
    for (int kc = 0; kc < 4; ++kc) {
      short8 wf = *(const short8*)(wp + df * 2048 + kc * 32);
      acc[df] = __builtin_amdgcn_mfma_f32_16x16x32_bf16(wf, hf[kc], acc[df], 0, 0, 0);
    }
  }

  #pragma unroll
  for (int df = 0; df < 4; ++df) {
    float4 b4 = *(const float4*)&bias[colbase + df * 16 + kg * 4];
    union { unsigned short us[4]; uint2 u2; } o;
    o.us[0] = f2b(acc[df][0] + b4.x);
    o.us[1] = f2b(acc[df][1] + b4.y);
    o.us[2] = f2b(acc[df][2] + b4.z);
    o.us[3] = f2b(acc[df][3] + b4.w);
    int colb = (colbase + df * 16 + kg * 4) * 2;
    *(uint2*)(cs + ro * ROWB + (colb ^ ((ro & 7) << 4))) = o.u2;
  }
  __syncthreads();

  unsigned char* dstb = (unsigned char*)(C + (size_t)blockIdx.x * 32 * 128);
  #pragma unroll
  for (int i = 0; i < 2; ++i) {
    int byte = (i * 256 + tid) * 16;
    int ro2 = byte / ROWB;
    int colb2 = byte & (ROWB - 1);
    *(uint4*)(dstb + byte) =
        *(const uint4*)(cs + ro2 * ROWB + (colb2 ^ ((ro2 & 7) << 4)));
  }
}

// ---------------- fused edge attention: score + softmax + g-aggregate ----------
// z is pre-scaled by log2(e): w = exp2(z.g) keeps exact softmax ratios.
__global__ __launch_bounds__(128) void edge_fused(
    const unsigned short* __restrict__ z, const unsigned short* __restrict__ g,
    const int* __restrict__ src, const int* __restrict__ row_start,
    unsigned short* __restrict__ gout)
{
  const int lane = threadIdx.x & 63;
  const int node = blockIdx.x * 2 + (threadIdx.x >> 6);
  const int sg = lane >> 4, sl = lane & 15;

  short8 qf = *(const short8*)(z + ((size_t)node << 7) + sl * 8);
  float qd[8];
  #pragma unroll
  for (int j = 0; j < 8; ++j) qd[j] = b2f((unsigned short)qf[j]);

  const int r0 = row_start[node], r1 = row_start[node + 1];

  float acc[8] = {0.f, 0.f, 0.f, 0.f, 0.f, 0.f, 0.f, 0.f};
  float ws = 0.f;

#define LOADG(VLD, HF, C)                                               \
  {                                                                     \
    int e_ = (C) + sg;                                                  \
    VLD = e_ < r1;                                                      \
    int s_ = VLD ? src[e_] : 0;                                         \
    HF = *(const short8*)(g + ((size_t)s_ << 7) + sl * 8);              \
  }

#define COMPG(VLD, HF)                                                  \
  {                                                                     \
    float hd_[8];                                                       \
    _Pragma("unroll")                                                   \
    for (int j = 0; j < 8; ++j) hd_[j] = b2f((unsigned short)HF[j]);    \
    float d0_ = 0.f, d1_ = 0.f;                                         \
    _Pragma("unroll")                                                   \
    for (int j = 0; j < 4; ++j) d0_ += qd[j] * hd_[j];                  \
    _Pragma("unroll")                                                   \
    for (int j = 4; j < 8; ++j) d1_ += qd[j] * hd_[j];                  \
    float d_ = d0_ + d1_;                                               \
    d_ += __shfl_xor(d_, 1, 64);                                        \
    d_ += __shfl_xor(d_, 2, 64);                                        \
    d_ += __shfl_xor(d_, 4, 64);                                        \
    d_ += __shfl_xor(d_, 8, 64);                                        \
    float w_ = VLD ? exp2f(d_) : 0.f;                                   \
    ws += w_;                                                           \
    _Pragma("unroll")                                                   \
    for (int j = 0; j < 8; ++j) acc[j] += w_ * hd_[j];                  \
  }

  bool vA, vB;
  short8 hA, hB;
  LOADG(vA, hA, r0);
  LOADG(vB, hB, r0 + 4);

  for (int c = r0; c < r1; c += 8) {
    bool vC, vD;
    short8 hC, hD;
    LOADG(vC, hC, c + 8);
    LOADG(vD, hD, c + 12);
    COMPG(vA, hA);
    COMPG(vB, hB);
    vA = vC; hA = hC;
    vB = vD; hB = hD;
  }

#undef LOADG
#undef COMPG

  #pragma unroll
  for (int off = 16; off <= 32; off <<= 1) {
    ws += __shfl_xor(ws, off, 64);
    #pragma unroll
    for (int j = 0; j < 8; ++j) acc[j] += __shfl_xor(acc[j], off, 64);
  }

  if (sg == 0) {
    float inv = (ws > 1e-20f) ? 1.0f / ws : 0.0f;
    union { unsigned short us[8]; uint4 u4; } o;
    #pragma unroll
    for (int j = 0; j < 8; ++j) o.us[j] = f2b(acc[j] * inv);
    *(uint4*)(gout + (size_t)node * 128 + sl * 8) = o.u4;
  }
}

// ---------------- output head via MFMA: logits + log_softmax -------------------
// grid 625, 16 rows/wave; LDS-staged contiguous f32 stores.
__global__ __launch_bounds__(256) void out_head_mfma(
    const unsigned short* __restrict__ h, const unsigned short* __restrict__ wout_t,
    const float* __restrict__ bout, float* __restrict__ out)
{
  __shared__ __align__(16) float os[64 * N_CLASSES];   // 10240 B

  const int wid = threadIdx.x >> 6, lane = threadIdx.x & 63;
  const int r = lane & 15, kg = lane >> 4;
  const int row_base = blockIdx.x * 64 + wid * 16;
  const int ar = row_base + r;

  floatx4 acc[3];
  #pragma unroll
  for (int n = 0; n < 3; ++n) acc[n] = (floatx4){0.f, 0.f, 0.f, 0.f};

  const unsigned short* ap = h + (size_t)ar * 128 + kg * 8;
  const unsigned short* bp = wout_t + (size_t)r * 128 + kg * 8;

  #pragma unroll
  for (int kc = 0; kc < 128; kc += 32) {
    short8 a0 = *(const short8*)(ap + kc);
    #pragma unroll
    for (int n = 0; n < 3; ++n) {
      short8 b = *(const short8*)(bp + n * 2048 + kc);
      acc[n] = __builtin_amdgcn_mfma_f32_16x16x32_bf16(a0, b, acc[n], 0, 0, 0);
    }
  }

  float bn0 = bout[r];
  float bn1 = bout[16 + r];
  float bn2 = (r < 8) ? bout[32 + r] : 0.f;

  #pragma unroll
  for (int g = 0; g < 4; ++g) {
    int rl = wid * 16 + kg * 4 + g;          // local row 0..63
    float l0 = acc[0][g] + bn0;
    float l1 = acc[1][g] + bn1;
    float l2 = acc[2][g] + bn2;              // valid only if r < 8
    float m = fmaxf(l0, l1);
    if (r < 8) m = fmaxf(m, l2);
    #pragma unroll
    for (int off = 8; off >= 1; off >>= 1) m = fmaxf(m, __shfl_xor(m, off, 64));
    float s = __expf(l0 - m) + __expf(l1 - m) + ((r < 8) ? __expf(l2 - m) : 0.f);
    #pragma unroll
    for (int off = 8; off >= 1; off >>= 1) s += __shfl_xor(s, off, 64);
    float lse = m + logf(s);
    os[rl * N_CLASSES + r]      = l0 - lse;
    os[rl * N_CLASSES + 16 + r] = l1 - lse;
    if (r < 8) os[rl * N_CLASSES + 32 + r] = l2 - lse;
  }
  __syncthreads();

  float* dstb = out + (size_t)blockIdx.x * 64 * N_CLASSES;
  #pragma unroll
  for (int i = 0; i < 3; ++i) {
    int idx = i * 256 + threadIdx.x;
    if (idx < 640)
      *(uint4*)(dstb + idx * 4) = *(const uint4*)(os + idx * 4);
  }
}

extern "C" void kernel_launch(void* const* d_in, const int* in_sizes, int n_in,
                              void* d_out, int out_size, void* d_ws, size_t ws_size,
                              hipStream_t stream) {
  const float* h_in = (const float*)d_in[0];
  const int*   src  = (const int*)d_in[1];
  const int*   dst  = (const int*)d_in[2];
  const float* Wq   = (const float*)d_in[3];
  const float* bq   = (const float*)d_in[4];
  const float* Wk   = (const float*)d_in[5];
  const float* bk   = (const float*)d_in[6];  // cancels in softmax (dst-constant)
  const float* Wv   = (const float*)d_in[7];
  const float* bv   = (const float*)d_in[8];
  const float* Wout = (const float*)d_in[9];
  const float* bout = (const float*)d_in[10];
  float* out = (float*)d_out;
  (void)bk;

  char* ws = (char*)d_ws;
  size_t off = 0;
  auto alloc = [&](size_t bytes) -> void* {
    void* p = ws + off;
    off += (bytes + 255) & ~(size_t)255;
    return p;
  };
  int*            row_start = (int*)           alloc((size_t)(N_NODES + 1) * sizeof(int));
  unsigned short* g0        = (unsigned short*)alloc((size_t)N_NODES * 128 * 2);
  unsigned short* g1        = (unsigned short*)alloc((size_t)N_NODES * 128 * 2);
  unsigned short* zbuf      = (unsigned short*)alloc((size_t)N_NODES * 128 * 2);
  unsigned short* WZ        = (unsigned short*)alloc((size_t)4 * 16384 * 2);
  unsigned short* WOt       = (unsigned short*)alloc((size_t)48 * 128 * 2);
  float*          D01  = (float*)alloc(16384 * 4);
  float*          D23  = (float*)alloc(16384 * 4);
  float*          A1f  = (float*)alloc(16384 * 4);
  float*          B1f  = (float*)alloc(16384 * 4);
  float*          E3   = (float*)alloc(16384 * 4);
  float*          F3   = (float*)alloc(16384 * 4);
  float*          A2f  = (float*)alloc(16384 * 4);
  float*          B2f  = (float*)alloc(16384 * 4);
  float*          A3f  = (float*)alloc(16384 * 4);
  float*          B3f  = (float*)alloc(16384 * 4);
  float*          C4f  = (float*)alloc(16384 * 4);
  float*          C3f  = (float*)alloc(16384 * 4);
  float*          zb   = (float*)alloc(4 * 128 * 4);
  float*          bout2 = (float*)alloc(64 * 4);

  auto J = [](const float* A, const float* B, float* Cf, unsigned short* Cb,
              float scale, int abt, int ncolsB, int storeT, int padrows) {
    MMJob j; j.A = A; j.B = B; j.Cf = Cf; j.Cb = Cb; j.scale = scale;
    j.abt = abt; j.ncolsB = ncolsB; j.storeT = storeT; j.padrows = padrows;
    return j;
  };
  const float* Wq_l[4] = {Wq, Wq + 16384, Wq + 32768, Wq + 49152};
  const float* Wk_l[4] = {Wk, Wk + 16384, Wk + 32768, Wk + 49152};
  const float* Wv_l[4] = {Wv, Wv + 16384, Wv + 32768, Wv + 49152};

  const float ZSC = SCALING * LOG2E;   // exp2 pre-scaling folded into WZ

  // stage 1: raw-input products
  MM7 s1;
  s1.j[0] = J(Wk_l[0], Wq_l[0], nullptr, WZ, ZSC, 1, 128, 0, 0);      // WZ0
  s1.j[1] = J(Wv_l[0], Wv_l[1], D01, nullptr, 1.f, 0, 128, 0, 0);
  s1.j[2] = J(Wv_l[2], Wv_l[3], D23, nullptr, 1.f, 0, 128, 0, 0);
  s1.j[3] = J(Wv_l[0], Wk_l[1], A1f, nullptr, 1.f, 0, 128, 0, 0);
  s1.j[4] = J(Wv_l[0], Wq_l[1], B1f, nullptr, 1.f, 0, 128, 0, 0);
  s1.j[5] = J(Wv_l[2], Wk_l[3], E3,  nullptr, 1.f, 0, 128, 0, 0);
  s1.j[6] = J(Wv_l[2], Wq_l[3], F3,  nullptr, 1.f, 0, 128, 0, 0);

  // stage 2
  MM7 s2;
  s2.j[0] = J(A1f, B1f, nullptr, WZ + 16384, ZSC, 1, 128, 0, 0);      // WZ1
  s2.j[1] = J(D01, Wk_l[2], A2f, nullptr, 1.f, 0, 128, 0, 0);
  s2.j[2] = J(D01, Wq_l[2], B2f, nullptr, 1.f, 0, 128, 0, 0);
  s2.j[3] = J(D01, E3, A3f, nullptr, 1.f, 0, 128, 0, 0);
  s2.j[4] = J(D01, F3, B3f, nullptr, 1.f, 0, 128, 0, 0);
  s2.j[5] = J(D01, D23, C4f, nullptr, 1.f, 0, 128, 0, 0);
  s2.j[6] = J(D01, Wv_l[2], C3f, nullptr, 1.f, 0, 128, 0, 0);

  // stage 3
  MM3 s3;
  s3.j[0] = J(A2f, B2f, nullptr, WZ + 32768, ZSC, 1, 128, 0, 0);      // WZ2
  s3.j[1] = J(A3f, B3f, nullptr, WZ + 49152, ZSC, 1, 128, 0, 0);      // WZ3
  s3.j[2] = J(C4f, Wout, nullptr, WOt, 1.f, 0, N_CLASSES, 1, 48);     // WOt

  setup_fold1<<<3106, 256, 0, stream>>>(h_in, dst, bq, Wk, g0, row_start, zb, s1);
  fold2<<<448, 256, 0, stream>>>(s2);
  fold3_z0<<<1443, 256, 0, stream>>>(s3, Wq, Wk, Wv, Wout, bq, bv, bout,
                                     D01, C3f, zb, bout2, g0, WZ, zbuf);

  // layer 0
  edge_fused<<<N_NODES / 2, 128, 0, stream>>>(zbuf, g0, src, row_start, g1);
  // layer 1
  gemm_z<<<1250, 256, 0, stream>>>(g1, WZ + 16384, zb + 128, zbuf);
  edge_fused<<<N_NODES / 2, 128, 0, stream>>>(zbuf, g1, src, row_start, g0);
  // layer 2
  gemm_z<<<1250, 256, 0, stream>>>(g0, WZ + 32768, zb + 256, zbuf);
  edge_fused<<<N_NODES / 2, 128, 0, stream>>>(zbuf, g0, src, row_start, g1);
  // layer 3
  gemm_z<<<1250, 256, 0, stream>>>(g1, WZ + 49152, zb + 384, zbuf);
  edge_fused<<<N_NODES / 2, 128, 0, stream>>>(zbuf, g1, src, row_start, g0);
  // head
  out_head_mfma<<<625, 256, 0, stream>>>(g0, WOt, bout2, out);
}

// Round 14
// 230.196 us; speedup vs baseline: 1.1075x; 1.0364x over previous
//
#include <hip/hip_runtime.h>
#include <math.h>

#define N_NODES 40000
#define N_EDGES 640000
#define HIDDEN 128
#define N_LAYERS 4
#define N_CLASSES 40
#define SCALING 0.08838834764831845f
#define LOG2E 1.4426950408889634f

typedef __attribute__((ext_vector_type(8))) short short8;
typedef __attribute__((ext_vector_type(4))) float floatx4;

static __device__ __forceinline__ float b2f(unsigned short u) {
  return __uint_as_float(((unsigned)u) << 16);
}
static __device__ __forceinline__ unsigned short f2b(float f) {
  unsigned u = __float_as_uint(f);
  u += 0x7fff + ((u >> 16) & 1);   // round-to-nearest-even
  return (unsigned short)(u >> 16);
}

// ---------------- f32 128x128 product jobs (weight folding) --------------------
struct MMJob {
  const float* A; const float* B;
  float* Cf; unsigned short* Cb;
  float scale;
  int abt; int ncolsB; int storeT; int padrows;
};
struct MM7 { MMJob j[7]; };
struct MM3 { MMJob j[3]; };

static __device__ __forceinline__ void run_job(const MMJob J, int bi) {
  int ty = threadIdx.x >> 7;        // 0..1
  int c  = threadIdx.x & 127;
  int r  = bi * 2 + ty;
  float acc = 0.f;
  if (J.abt) {
    const float* ar = J.A + (size_t)r * 128;
    const float* br = J.B + (size_t)c * 128;
    #pragma unroll 4
    for (int j = 0; j < 128; ++j) acc += ar[j] * br[j];
  } else if (c < J.ncolsB) {
    const float* ar = J.A + (size_t)r * 128;
    #pragma unroll 4
    for (int j = 0; j < 128; ++j) acc += ar[j] * J.B[(size_t)j * J.ncolsB + c];
  }
  acc *= J.scale;
  if (J.storeT) {
    if (c < J.ncolsB) {
      if (J.Cb) J.Cb[(size_t)c * 128 + r] = f2b(acc);
      else      J.Cf[(size_t)c * 128 + r] = acc;
    } else if (c < J.padrows && J.Cb) {
      J.Cb[(size_t)c * 128 + r] = 0;
    }
  } else if (c < J.ncolsB) {
    if (J.Cb) J.Cb[(size_t)r * J.ncolsB + c] = f2b(acc);
    else      J.Cf[(size_t)r * J.ncolsB + c] = acc;
  }
}

// ---------------- K1: setup (cast h0, CSR) + fold stage 1 + zb0 ----------------
__global__ __launch_bounds__(256) void setup_fold1(
    const float* __restrict__ h_in, const int* __restrict__ dst,
    const float* __restrict__ bq, const float* __restrict__ Wk,
    unsigned short* __restrict__ g0, int* __restrict__ row_start,
    float* __restrict__ zb, MM7 st)
{
  int blk = blockIdx.x;
  if (blk < 2657) {
    int idx = blk * 256 + threadIdx.x;
    if (idx < 640000) {
      const float4* p = (const float4*)h_in + (size_t)idx * 2;
      float4 a = p[0], b = p[1];
      union { unsigned short us[8]; uint4 v; } o;
      o.us[0] = f2b(a.x); o.us[1] = f2b(a.y); o.us[2] = f2b(a.z); o.us[3] = f2b(a.w);
      o.us[4] = f2b(b.x); o.us[5] = f2b(b.y); o.us[6] = f2b(b.z); o.us[7] = f2b(b.w);
      ((uint4*)g0)[idx] = o.v;
      return;
    }
    int c = idx - 640000;
    if (c <= N_NODES) {
      int lo = 0, hi = N_EDGES;
      while (lo < hi) {
        int mid = (lo + hi) >> 1;
        if (dst[mid] < c) lo = mid + 1; else hi = mid;
      }
      row_start[c] = lo;
    }
    return;
  }
  if (blk < 3105) {
    int b2 = blk - 2657;
    run_job(st.j[b2 >> 6], b2 & 63);
    return;
  }
  // zb layer 0 (exp2-prescaled): 2-way split dot, pipelined loads
  {
    __shared__ float part[2][128];
    int t = threadIdx.x, h = t >> 7, tt = t & 127;
    const float* wkr = Wk + (size_t)tt * 128 + h * 64;
    const float* bqh = bq + h * 64;
    float s = 0.f;
    #pragma unroll
    for (int o = 0; o < 64; ++o) s += bqh[o] * wkr[o];
    part[h][tt] = s;
    __syncthreads();
    if (t < 128) zb[t] = (part[0][t] + part[1][t]) * (SCALING * LOG2E);
  }
}

// ---------------- K2: fold stage 2 (7 jobs x 64 blocks) ------------------------
__global__ __launch_bounds__(256) void fold2(MM7 st) {
  run_job(st.j[blockIdx.x >> 6], blockIdx.x & 63);
}

// ---------------- K3: fold stage 3 + bias chain + gemm_z layer 0 ---------------
__global__ __launch_bounds__(256) void fold3_z0(
    MM3 st,
    const float* __restrict__ Wq, const float* __restrict__ Wk,
    const float* __restrict__ Wv, const float* __restrict__ Wout,
    const float* __restrict__ bq, const float* __restrict__ bv,
    const float* __restrict__ bout,
    const float* __restrict__ D01, const float* __restrict__ C3f,
    float* __restrict__ zb, float* __restrict__ bout2,
    const unsigned short* __restrict__ g, const unsigned short* __restrict__ WZ0,
    unsigned short* __restrict__ zout)
{
  int blk = blockIdx.x;
  if (blk < 192) {
    run_job(st.j[blk >> 6], blk & 63);
    return;
  }
  if (blk == 192) {
    // bias chain (zeros in this dataset, kept for exactness).
    // All mat-vecs 2-way thread-split with fully-unrolled 64-term half-dots.
    int t = threadIdx.x, h = t >> 7, tt = t & 127;
    __shared__ float cb[128], v1[128], v2[128], part[2][128];
    if (t < 128) cb[t] = bv[t];
    __syncthreads();
    for (int l = 1; l < 4; ++l) {
      const float* Cvl = (l == 1) ? Wv : (l == 2 ? D01 : C3f);
      // v1[t] = bq_l[t] + sum_o cb[o] * Wq_l[o][t]
      {
        const float* M = Wq + (size_t)l * 16384 + (size_t)h * 64 * 128 + tt;
        float s = 0.f;
        #pragma unroll
        for (int o = 0; o < 64; ++o) s += cb[h * 64 + o] * M[(size_t)o * 128];
        part[h][tt] = s;
        __syncthreads();
        if (t < 128) v1[t] = part[0][t] + part[1][t] + bq[(size_t)l * 128 + t];
        __syncthreads();
      }
      // v2[t] = sum_o v1[o] * Wk_l[t][o]
      {
        const float* M = Wk + (size_t)l * 16384 + (size_t)tt * 128 + h * 64;
        float s = 0.f;
        #pragma unroll
        for (int o = 0; o < 64; ++o) s += v1[h * 64 + o] * M[o];
        part[h][tt] = s;
        __syncthreads();
        if (t < 128) v2[t] = part[0][t] + part[1][t];
        __syncthreads();
      }
      // zb_l[t] = ZSC * sum_d v2[d] * Cvl[t][d]
      {
        const float* M = Cvl + (size_t)tt * 128 + h * 64;
        float s = 0.f;
        #pragma unroll
        for (int d = 0; d < 64; ++d) s += v2[h * 64 + d] * M[d];
        part[h][tt] = s;
        __syncthreads();
        if (t < 128)
          zb[(size_t)l * 128 + t] = (part[0][t] + part[1][t]) * (SCALING * LOG2E);
        __syncthreads();
      }
      // cb[t] <- bv_l[t] + sum_d cb[d] * Wv_l[d][t]
      {
        const float* M = Wv + (size_t)l * 16384 + (size_t)h * 64 * 128 + tt;
        float s = 0.f;
        #pragma unroll
        for (int d = 0; d < 64; ++d) s += cb[h * 64 + d] * M[(size_t)d * 128];
        part[h][tt] = s;
        __syncthreads();
        if (t < 128) cb[t] = part[0][t] + part[1][t] + bv[(size_t)l * 128 + t];
        __syncthreads();
      }
    }
    // bout2[c] = bout[c] + sum_d cb[d] * Wout[d][c]
    {
      float s = 0.f;
      if (tt < N_CLASSES) {
        const float* M = Wout + (size_t)h * 64 * N_CLASSES + tt;
        #pragma unroll
        for (int d = 0; d < 64; ++d) s += cb[h * 64 + d] * M[(size_t)d * N_CLASSES];
      }
      part[h][tt] = s;
      __syncthreads();
      if (t < N_CLASSES) bout2[t] = part[0][t] + part[1][t] + bout[t];
    }
    return;
  }

  // ---- gemm_z for layer 0 ----
  {
    const int tile = blk - 193;                 // 0..1249
    constexpr int ROWB = 256;
    __shared__ __align__(16) unsigned char cs[32 * ROWB];

    const int tid = threadIdx.x;
    const int wid = tid >> 6, lane = tid & 63;
    const int r = lane & 15, kg = lane >> 4;
    const int colhalf = wid & 1, rowsub = wid >> 1;
    const int colbase = colhalf * 64;
    const int ro = rowsub * 16 + r;
    const int row = tile * 32 + ro;

    short8 hf[4];
    #pragma unroll
    for (int kc = 0; kc < 4; ++kc)
      hf[kc] = *(const short8*)(g + (size_t)row * 128 + kc * 32 + kg * 8);

    floatx4 acc[4];
    #pragma unroll
    for (int df = 0; df < 4; ++df) acc[df] = (floatx4){0.f, 0.f, 0.f, 0.f};

    const unsigned short* wp = WZ0 + (size_t)(colbase + r) * 128 + kg * 8;
    #pragma unroll
    for (int df = 0; df < 4; ++df) {
      #pragma unroll
      for (int kc = 0; kc < 4; ++kc) {
        short8 wf = *(const short8*)(wp + df * 2048 + kc * 32);
        acc[df] = __builtin_amdgcn_mfma_f32_16x16x32_bf16(wf, hf[kc], acc[df], 0, 0, 0);
      }
    }

    #pragma unroll
    for (int df = 0; df < 4; ++df) {
      float4 b4 = *(const float4*)&zb[colbase + df * 16 + kg * 4];
      union { unsigned short us[4]; uint2 u2; } o;
      o.us[0] = f2b(acc[df][0] + b4.x);
      o.us[1] = f2b(acc[df][1] + b4.y);
      o.us[2] = f2b(acc[df][2] + b4.z);
      o.us[3] = f2b(acc[df][3] + b4.w);
      int colb = (colbase + df * 16 + kg * 4) * 2;
      *(uint2*)(cs + ro * ROWB + (colb ^ ((ro & 7) << 4))) = o.u2;
    }
    __syncthreads();

    unsigned char* dstb = (unsigned char*)(zout + (size_t)tile * 32 * 128);
    #pragma unroll
    for (int i = 0; i < 2; ++i) {
      int byte = (i * 256 + tid) * 16;
      int ro2 = byte / ROWB;
      int colb2 = byte & (ROWB - 1);
      *(uint4*)(dstb + byte) =
          *(const uint4*)(cs + ro2 * ROWB + (colb2 ^ ((ro2 & 7) << 4)));
    }
  }
}

// ---------------- node GEMM via MFMA bf16, LDS-staged coalesced epilogue -------
__global__ __launch_bounds__(256) void gemm_z(
    const unsigned short* __restrict__ A,
    const unsigned short* __restrict__ Wt,
    const float* __restrict__ bias,
    unsigned short* __restrict__ C)
{
  constexpr int ROWB = 256;
  __shared__ __align__(16) unsigned char cs[32 * ROWB];

  const int tid = threadIdx.x;
  const int wid = tid >> 6, lane = tid & 63;
  const int r = lane & 15, kg = lane >> 4;
  const int colhalf = wid & 1, rowsub = wid >> 1;
  const int colbase = colhalf * 64;
  const int ro = rowsub * 16 + r;
  const int row = blockIdx.x * 32 + ro;

  short8 hf[4];
  #pragma unroll
  for (int kc = 0; kc < 4; ++kc)
    hf[kc] = *(const short8*)(A + (size_t)row * 128 + kc * 32 + kg * 8);

  floatx4 acc[4];
  #pragma unroll
  for (int df = 0; df < 4; ++df) acc[df] = (floatx4){0.f, 0.f, 0.f, 0.f};

  const unsigned short* wp = Wt + (size_t)(colbase + r) * 128 + kg * 8;
  #pragma unroll
  for (int df = 0; df < 4; ++df) {
    #pragma unroll
    for (int kc = 0; kc < 4; ++kc) {
      short8 wf = *(const short8*)(wp + df * 2048 + kc * 32);
      acc[df] = __builtin_amdgcn_mfma_f32_16x16x32_bf16(wf, hf[kc], acc[df], 0, 0, 0);
    }
  }

  #pragma unroll
  for (int df = 0; df < 4; ++df) {
    float4 b4 = *(const float4*)&bias[colbase + df * 16 + kg * 4];
    union { unsigned short us[4]; uint2 u2; } o;
    o.us[0] = f2b(acc[df][0] + b4.x);
    o.us[1] = f2b(acc[df][1] + b4.y);
    o.us[2] = f2b(acc[df][2] + b4.z);
    o.us[3] = f2b(acc[df][3] + b4.w);
    int colb = (colbase + df * 16 + kg * 4) * 2;
    *(uint2*)(cs + ro * ROWB + (colb ^ ((ro & 7) << 4))) = o.u2;
  }
  __syncthreads();

  unsigned char* dstb = (unsigned char*)(C + (size_t)blockIdx.x * 32 * 128);
  #pragma unroll
  for (int i = 0; i < 2; ++i) {
    int byte = (i * 256 + tid) * 16;
    int ro2 = byte / ROWB;
    int colb2 = byte & (ROWB - 1);
    *(uint4*)(dstb + byte) =
        *(const uint4*)(cs + ro2 * ROWB + (colb2 ^ ((ro2 & 7) << 4)));
  }
}

// ---------------- fused edge attention: score + softmax + g-aggregate ----------
// z is pre-scaled by log2(e): w = exp2(z.g) keeps exact softmax ratios.
__global__ __launch_bounds__(128) void edge_fused(
    const unsigned short* __restrict__ z, const unsigned short* __restrict__ g,
    const int* __restrict__ src, const int* __restrict__ row_start,
    unsigned short* __restrict__ gout)
{
  const int lane = threadIdx.x & 63;
  const int node = blockIdx.x * 2 + (threadIdx.x >> 6);
  const int sg = lane >> 4, sl = lane & 15;

  short8 qf = *(const short8*)(z + ((size_t)node << 7) + sl * 8);
  float qd[8];
  #pragma unroll
  for (int j = 0; j < 8; ++j) qd[j] = b2f((unsigned short)qf[j]);

  const int r0 = row_start[node], r1 = row_start[node + 1];

  float acc[8] = {0.f, 0.f, 0.f, 0.f, 0.f, 0.f, 0.f, 0.f};
  float ws = 0.f;

#define LOADG(VLD, HF, C)                                               \
  {                                                                     \
    int e_ = (C) + sg;                                                  \
    VLD = e_ < r1;                                                      \
    int s_ = VLD ? src[e_] : 0;                                         \
    HF = *(const short8*)(g + ((size_t)s_ << 7) + sl * 8);              \
  }

#define COMPG(VLD, HF)                                                  \
  {                                                                     \
    float hd_[8];                                                       \
    _Pragma("unroll")                                                   \
    for (int j = 0; j < 8; ++j) hd_[j] = b2f((unsigned short)HF[j]);    \
    float d0_ = 0.f, d1_ = 0.f;                                         \
    _Pragma("unroll")                                                   \
    for (int j = 0; j < 4; ++j) d0_ += qd[j] * hd_[j];                  \
    _Pragma("unroll")                                                   \
    for (int j = 4; j < 8; ++j) d1_ += qd[j] * hd_[j];                  \
    float d_ = d0_ + d1_;                                               \
    d_ += __shfl_xor(d_, 1, 64);                                        \
    d_ += __shfl_xor(d_, 2, 64);                                        \
    d_ += __shfl_xor(d_, 4, 64);                                        \
    d_ += __shfl_xor(d_, 8, 64);                                        \
    float w_ = VLD ? exp2f(d_) : 0.f;                                   \
    ws += w_;                                                           \
    _Pragma("unroll")                                                   \
    for (int j = 0; j < 8; ++j) acc[j] += w_ * hd_[j];                  \
  }

  bool vA, vB;
  short8 hA, hB;
  LOADG(vA, hA, r0);
  LOADG(vB, hB, r0 + 4);

  for (int c = r0; c < r1; c += 8) {
    bool vC, vD;
    short8 hC, hD;
    LOADG(vC, hC, c + 8);
    LOADG(vD, hD, c + 12);
    COMPG(vA, hA);
    COMPG(vB, hB);
    vA = vC; hA = hC;
    vB = vD; hB = hD;
  }

#undef LOADG
#undef COMPG

  #pragma unroll
  for (int off = 16; off <= 32; off <<= 1) {
    ws += __shfl_xor(ws, off, 64);
    #pragma unroll
    for (int j = 0; j < 8; ++j) acc[j] += __shfl_xor(acc[j], off, 64);
  }

  if (sg == 0) {
    float inv = (ws > 1e-20f) ? 1.0f / ws : 0.0f;
    union { unsigned short us[8]; uint4 u4; } o;
    #pragma unroll
    for (int j = 0; j < 8; ++j) o.us[j] = f2b(acc[j] * inv);
    *(uint4*)(gout + (size_t)node * 128 + sl * 8) = o.u4;
  }
}

// ---------------- output head via MFMA: logits + log_softmax -------------------
__global__ __launch_bounds__(256) void out_head_mfma(
    const unsigned short* __restrict__ h, const unsigned short* __restrict__ wout_t,
    const float* __restrict__ bout, float* __restrict__ out)
{
  __shared__ __align__(16) float os[64 * N_CLASSES];   // 10240 B

  const int wid = threadIdx.x >> 6, lane = threadIdx.x & 63;
  const int r = lane & 15, kg = lane >> 4;
  const int row_base = blockIdx.x * 64 + wid * 16;
  const int ar = row_base + r;

  floatx4 acc[3];
  #pragma unroll
  for (int n = 0; n < 3; ++n) acc[n] = (floatx4){0.f, 0.f, 0.f, 0.f};

  const unsigned short* ap = h + (size_t)ar * 128 + kg * 8;
  const unsigned short* bp = wout_t + (size_t)r * 128 + kg * 8;

  #pragma unroll
  for (int kc = 0; kc < 128; kc += 32) {
    short8 a0 = *(const short8*)(ap + kc);
    #pragma unroll
    for (int n = 0; n < 3; ++n) {
      short8 b = *(const short8*)(bp + n * 2048 + kc);
      acc[n] = __builtin_amdgcn_mfma_f32_16x16x32_bf16(a0, b, acc[n], 0, 0, 0);
    }
  }

  float bn0 = bout[r];
  float bn1 = bout[16 + r];
  float bn2 = (r < 8) ? bout[32 + r] : 0.f;

  #pragma unroll
  for (int g = 0; g < 4; ++g) {
    int rl = wid * 16 + kg * 4 + g;          // local row 0..63
    float l0 = acc[0][g] + bn0;
    float l1 = acc[1][g] + bn1;
    float l2 = acc[2][g] + bn2;              // valid only if r < 8
    float m = fmaxf(l0, l1);
    if (r < 8) m = fmaxf(m, l2);
    #pragma unroll
    for (int off = 8; off >= 1; off >>= 1) m = fmaxf(m, __shfl_xor(m, off, 64));
    float s = __expf(l0 - m) + __expf(l1 - m) + ((r < 8) ? __expf(l2 - m) : 0.f);
    #pragma unroll
    for (int off = 8; off >= 1; off >>= 1) s += __shfl_xor(s, off, 64);
    float lse = m + logf(s);
    os[rl * N_CLASSES + r]      = l0 - lse;
    os[rl * N_CLASSES + 16 + r] = l1 - lse;
    if (r < 8) os[rl * N_CLASSES + 32 + r] = l2 - lse;
  }
  __syncthreads();

  float* dstb = out + (size_t)blockIdx.x * 64 * N_CLASSES;
  #pragma unroll
  for (int i = 0; i < 3; ++i) {
    int idx = i * 256 + threadIdx.x;
    if (idx < 640)
      *(uint4*)(dstb + idx * 4) = *(const uint4*)(os + idx * 4);
  }
}

extern "C" void kernel_launch(void* const* d_in, const int* in_sizes, int n_in,
                              void* d_out, int out_size, void* d_ws, size_t ws_size,
                              hipStream_t stream) {
  const float* h_in = (const float*)d_in[0];
  const int*   src  = (const int*)d_in[1];
  const int*   dst  = (const int*)d_in[2];
  const float* Wq   = (const float*)d_in[3];
  const float* bq   = (const float*)d_in[4];
  const float* Wk   = (const float*)d_in[5];
  const float* bk   = (const float*)d_in[6];  // cancels in softmax (dst-constant)
  const float* Wv   = (const float*)d_in[7];
  const float* bv   = (const float*)d_in[8];
  const float* Wout = (const float*)d_in[9];
  const float* bout = (const float*)d_in[10];
  float* out = (float*)d_out;
  (void)bk;

  char* ws = (char*)d_ws;
  size_t off = 0;
  auto alloc = [&](size_t bytes) -> void* {
    void* p = ws + off;
    off += (bytes + 255) & ~(size_t)255;
    return p;
  };
  int*            row_start = (int*)           alloc((size_t)(N_NODES + 1) * sizeof(int));
  unsigned short* g0        = (unsigned short*)alloc((size_t)N_NODES * 128 * 2);
  unsigned short* g1        = (unsigned short*)alloc((size_t)N_NODES * 128 * 2);
  unsigned short* zbuf      = (unsigned short*)alloc((size_t)N_NODES * 128 * 2);
  unsigned short* WZ        = (unsigned short*)alloc((size_t)4 * 16384 * 2);
  unsigned short* WOt       = (unsigned short*)alloc((size_t)48 * 128 * 2);
  float*          D01  = (float*)alloc(16384 * 4);
  float*          D23  = (float*)alloc(16384 * 4);
  float*          A1f  = (float*)alloc(16384 * 4);
  float*          B1f  = (float*)alloc(16384 * 4);
  float*          E3   = (float*)alloc(16384 * 4);
  float*          F3   = (float*)alloc(16384 * 4);
  float*          A2f  = (float*)alloc(16384 * 4);
  float*          B2f  = (float*)alloc(16384 * 4);
  float*          A3f  = (float*)alloc(16384 * 4);
  float*          B3f  = (float*)alloc(16384 * 4);
  float*          C4f  = (float*)alloc(16384 * 4);
  float*          C3f  = (float*)alloc(16384 * 4);
  float*          zb   = (float*)alloc(4 * 128 * 4);
  float*          bout2 = (float*)alloc(64 * 4);

  auto J = [](const float* A, const float* B, float* Cf, unsigned short* Cb,
              float scale, int abt, int ncolsB, int storeT, int padrows) {
    MMJob j; j.A = A; j.B = B; j.Cf = Cf; j.Cb = Cb; j.scale = scale;
    j.abt = abt; j.ncolsB = ncolsB; j.storeT = storeT; j.padrows = padrows;
    return j;
  };
  const float* Wq_l[4] = {Wq, Wq + 16384, Wq + 32768, Wq + 49152};
  const float* Wk_l[4] = {Wk, Wk + 16384, Wk + 32768, Wk + 49152};
  const float* Wv_l[4] = {Wv, Wv + 16384, Wv + 32768, Wv + 49152};

  const float ZSC = SCALING * LOG2E;   // exp2 pre-scaling folded into WZ

  // stage 1: raw-input products
  MM7 s1;
  s1.j[0] = J(Wk_l[0], Wq_l[0], nullptr, WZ, ZSC, 1, 128, 0, 0);      // WZ0
  s1.j[1] = J(Wv_l[0], Wv_l[1], D01, nullptr, 1.f, 0, 128, 0, 0);
  s1.j[2] = J(Wv_l[2], Wv_l[3], D23, nullptr, 1.f, 0, 128, 0, 0);
  s1.j[3] = J(Wv_l[0], Wk_l[1], A1f, nullptr, 1.f, 0, 128, 0, 0);
  s1.j[4] = J(Wv_l[0], Wq_l[1], B1f, nullptr, 1.f, 0, 128, 0, 0);
  s1.j[5] = J(Wv_l[2], Wk_l[3], E3,  nullptr, 1.f, 0, 128, 0, 0);
  s1.j[6] = J(Wv_l[2], Wq_l[3], F3,  nullptr, 1.f, 0, 128, 0, 0);

  // stage 2
  MM7 s2;
  s2.j[0] = J(A1f, B1f, nullptr, WZ + 16384, ZSC, 1, 128, 0, 0);      // WZ1
  s2.j[1] = J(D01, Wk_l[2], A2f, nullptr, 1.f, 0, 128, 0, 0);
  s2.j[2] = J(D01, Wq_l[2], B2f, nullptr, 1.f, 0, 128, 0, 0);
  s2.j[3] = J(D01, E3, A3f, nullptr, 1.f, 0, 128, 0, 0);
  s2.j[4] = J(D01, F3, B3f, nullptr, 1.f, 0, 128, 0, 0);
  s2.j[5] = J(D01, D23, C4f, nullptr, 1.f, 0, 128, 0, 0);
  s2.j[6] = J(D01, Wv_l[2], C3f, nullptr, 1.f, 0, 128, 0, 0);

  // stage 3
  MM3 s3;
  s3.j[0] = J(A2f, B2f, nullptr, WZ + 32768, ZSC, 1, 128, 0, 0);      // WZ2
  s3.j[1] = J(A3f, B3f, nullptr, WZ + 49152, ZSC, 1, 128, 0, 0);      // WZ3
  s3.j[2] = J(C4f, Wout, nullptr, WOt, 1.f, 0, N_CLASSES, 1, 48);     // WOt

  setup_fold1<<<3106, 256, 0, stream>>>(h_in, dst, bq, Wk, g0, row_start, zb, s1);
  fold2<<<448, 256, 0, stream>>>(s2);
  fold3_z0<<<1443, 256, 0, stream>>>(s3, Wq, Wk, Wv, Wout, bq, bv, bout,
                                     D01, C3f, zb, bout2, g0, WZ, zbuf);

  // layer 0
  edge_fused<<<N_NODES / 2, 128, 0, stream>>>(zbuf, g0, src, row_start, g1);
  // layer 1
  gemm_z<<<1250, 256, 0, stream>>>(g1, WZ + 16384, zb + 128, zbuf);
  edge_fused<<<N_NODES / 2, 128, 0, stream>>>(zbuf, g1, src, row_start, g0);
  // layer 2
  gemm_z<<<1250, 256, 0, stream>>>(g0, WZ + 32768, zb + 256, zbuf);
  edge_fused<<<N_NODES / 2, 128, 0, stream>>>(zbuf, g0, src, row_start, g1);
  // layer 3
  gemm_z<<<1250, 256, 0, stream>>>(g1, WZ + 49152, zb + 384, zbuf);
  edge_fused<<<N_NODES / 2, 128, 0, stream>>>(zbuf, g1, src, row_start, g0);
  // head
  out_head_mfma<<<625, 256, 0, stream>>>(g0, WOt, bout2, out);
}

// Round 15
// 224.218 us; speedup vs baseline: 1.1370x; 1.0267x over previous
//
#include <hip/hip_runtime.h>
#include <math.h>

#define N_NODES 40000
#define N_EDGES 640000
#define HIDDEN 128
#define N_LAYERS 4
#define N_CLASSES 40
#define SCALING 0.08838834764831845f
#define LOG2E 1.4426950408889634f

typedef __attribute__((ext_vector_type(8))) short short8;
typedef __attribute__((ext_vector_type(4))) float floatx4;

static __device__ __forceinline__ float b2f(unsigned short u) {
  return __uint_as_float(((unsigned)u) << 16);
}
static __device__ __forceinline__ unsigned short f2b(float f) {
  unsigned u = __float_as_uint(f);
  u += 0x7fff + ((u >> 16) & 1);   // round-to-nearest-even
  return (unsigned short)(u >> 16);
}

// 16-lane (DPP row) sum: quad_perm xor1, xor2, then row_ror:4, row_ror:8.
// Pure VALU — no ds_bpermute on the score critical path.
static __device__ __forceinline__ float row16_sum(float d) {
  int x;
  x = __builtin_amdgcn_update_dpp(0, __float_as_int(d), 0xB1, 0xF, 0xF, true);
  d += __int_as_float(x);
  x = __builtin_amdgcn_update_dpp(0, __float_as_int(d), 0x4E, 0xF, 0xF, true);
  d += __int_as_float(x);
  x = __builtin_amdgcn_update_dpp(0, __float_as_int(d), 0x124, 0xF, 0xF, true);
  d += __int_as_float(x);
  x = __builtin_amdgcn_update_dpp(0, __float_as_int(d), 0x128, 0xF, 0xF, true);
  d += __int_as_float(x);
  return d;
}

// ---------------- f32 128x128 product jobs (weight folding) --------------------
struct MMJob {
  const float* A; const float* B;
  float* Cf; unsigned short* Cb;
  float scale;
  int abt; int ncolsB; int storeT; int padrows;
};
struct MM7 { MMJob j[7]; };
struct MM3 { MMJob j[3]; };

static __device__ __forceinline__ void run_job(const MMJob J, int bi) {
  int ty = threadIdx.x >> 7;        // 0..1
  int c  = threadIdx.x & 127;
  int r  = bi * 2 + ty;
  float acc = 0.f;
  if (J.abt) {
    const float* ar = J.A + (size_t)r * 128;
    const float* br = J.B + (size_t)c * 128;
    #pragma unroll 4
    for (int j = 0; j < 128; ++j) acc += ar[j] * br[j];
  } else if (c < J.ncolsB) {
    const float* ar = J.A + (size_t)r * 128;
    #pragma unroll 4
    for (int j = 0; j < 128; ++j) acc += ar[j] * J.B[(size_t)j * J.ncolsB + c];
  }
  acc *= J.scale;
  if (J.storeT) {
    if (c < J.ncolsB) {
      if (J.Cb) J.Cb[(size_t)c * 128 + r] = f2b(acc);
      else      J.Cf[(size_t)c * 128 + r] = acc;
    } else if (c < J.padrows && J.Cb) {
      J.Cb[(size_t)c * 128 + r] = 0;
    }
  } else if (c < J.ncolsB) {
    if (J.Cb) J.Cb[(size_t)r * J.ncolsB + c] = f2b(acc);
    else      J.Cf[(size_t)r * J.ncolsB + c] = acc;
  }
}

// ---------------- K1: setup (cast h0, CSR) + fold stage 1 + zb0 ----------------
__global__ __launch_bounds__(256) void setup_fold1(
    const float* __restrict__ h_in, const int* __restrict__ dst,
    const float* __restrict__ bq, const float* __restrict__ Wk,
    unsigned short* __restrict__ g0, int* __restrict__ row_start,
    float* __restrict__ zb, MM7 st)
{
  int blk = blockIdx.x;
  if (blk < 2657) {
    int idx = blk * 256 + threadIdx.x;
    if (idx < 640000) {
      const float4* p = (const float4*)h_in + (size_t)idx * 2;
      float4 a = p[0], b = p[1];
      union { unsigned short us[8]; uint4 v; } o;
      o.us[0] = f2b(a.x); o.us[1] = f2b(a.y); o.us[2] = f2b(a.z); o.us[3] = f2b(a.w);
      o.us[4] = f2b(b.x); o.us[5] = f2b(b.y); o.us[6] = f2b(b.z); o.us[7] = f2b(b.w);
      ((uint4*)g0)[idx] = o.v;
      return;
    }
    int c = idx - 640000;
    if (c <= N_NODES) {
      int lo = 0, hi = N_EDGES;
      while (lo < hi) {
        int mid = (lo + hi) >> 1;
        if (dst[mid] < c) lo = mid + 1; else hi = mid;
      }
      row_start[c] = lo;
    }
    return;
  }
  if (blk < 3105) {
    int b2 = blk - 2657;
    run_job(st.j[b2 >> 6], b2 & 63);
    return;
  }
  // zb layer 0 (exp2-prescaled): 2-way split dot, pipelined loads
  {
    __shared__ float part[2][128];
    int t = threadIdx.x, h = t >> 7, tt = t & 127;
    const float* wkr = Wk + (size_t)tt * 128 + h * 64;
    const float* bqh = bq + h * 64;
    float s = 0.f;
    #pragma unroll
    for (int o = 0; o < 64; ++o) s += bqh[o] * wkr[o];
    part[h][tt] = s;
    __syncthreads();
    if (t < 128) zb[t] = (part[0][t] + part[1][t]) * (SCALING * LOG2E);
  }
}

// ---------------- K2: fold stage 2 (7 jobs x 64 blocks) ------------------------
__global__ __launch_bounds__(256) void fold2(MM7 st) {
  run_job(st.j[blockIdx.x >> 6], blockIdx.x & 63);
}

// ---------------- K3: fold stage 3 + bias chain + gemm_z layer 0 ---------------
__global__ __launch_bounds__(256) void fold3_z0(
    MM3 st,
    const float* __restrict__ Wq, const float* __restrict__ Wk,
    const float* __restrict__ Wv, const float* __restrict__ Wout,
    const float* __restrict__ bq, const float* __restrict__ bv,
    const float* __restrict__ bout,
    const float* __restrict__ D01, const float* __restrict__ C3f,
    float* __restrict__ zb, float* __restrict__ bout2,
    const unsigned short* __restrict__ g, const unsigned short* __restrict__ WZ0,
    unsigned short* __restrict__ zout)
{
  int blk = blockIdx.x;
  if (blk < 192) {
    run_job(st.j[blk >> 6], blk & 63);
    return;
  }
  if (blk == 192) {
    // bias chain (zeros in this dataset, kept for exactness).
    int t = threadIdx.x, h = t >> 7, tt = t & 127;
    __shared__ float cb[128], v1[128], v2[128], part[2][128];
    if (t < 128) cb[t] = bv[t];
    __syncthreads();
    for (int l = 1; l < 4; ++l) {
      const float* Cvl = (l == 1) ? Wv : (l == 2 ? D01 : C3f);
      {
        const float* M = Wq + (size_t)l * 16384 + (size_t)h * 64 * 128 + tt;
        float s = 0.f;
        #pragma unroll
        for (int o = 0; o < 64; ++o) s += cb[h * 64 + o] * M[(size_t)o * 128];
        part[h][tt] = s;
        __syncthreads();
        if (t < 128) v1[t] = part[0][t] + part[1][t] + bq[(size_t)l * 128 + t];
        __syncthreads();
      }
      {
        const float* M = Wk + (size_t)l * 16384 + (size_t)tt * 128 + h * 64;
        float s = 0.f;
        #pragma unroll
        for (int o = 0; o < 64; ++o) s += v1[h * 64 + o] * M[o];
        part[h][tt] = s;
        __syncthreads();
        if (t < 128) v2[t] = part[0][t] + part[1][t];
        __syncthreads();
      }
      {
        const float* M = Cvl + (size_t)tt * 128 + h * 64;
        float s = 0.f;
        #pragma unroll
        for (int d = 0; d < 64; ++d) s += v2[h * 64 + d] * M[d];
        part[h][tt] = s;
        __syncthreads();
        if (t < 128)
          zb[(size_t)l * 128 + t] = (part[0][t] + part[1][t]) * (SCALING * LOG2E);
        __syncthreads();
      }
      {
        const float* M = Wv + (size_t)l * 16384 + (size_t)h * 64 * 128 + tt;
        float s = 0.f;
        #pragma unroll
        for (int d = 0; d < 64; ++d) s += cb[h * 64 + d] * M[(size_t)d * 128];
        part[h][tt] = s;
        __syncthreads();
        if (t < 128) cb[t] = part[0][t] + part[1][t] + bv[(size_t)l * 128 + t];
        __syncthreads();
      }
    }
    {
      float s = 0.f;
      if (tt < N_CLASSES) {
        const float* M = Wout + (size_t)h * 64 * N_CLASSES + tt;
        #pragma unroll
        for (int d = 0; d < 64; ++d) s += cb[h * 64 + d] * M[(size_t)d * N_CLASSES];
      }
      part[h][tt] = s;
      __syncthreads();
      if (t < N_CLASSES) bout2[t] = part[0][t] + part[1][t] + bout[t];
    }
    return;
  }

  // ---- gemm_z for layer 0 ----
  {
    const int tile = blk - 193;                 // 0..1249
    constexpr int ROWB = 256;
    __shared__ __align__(16) unsigned char cs[32 * ROWB];

    const int tid = threadIdx.x;
    const int wid = tid >> 6, lane = tid & 63;
    const int r = lane & 15, kg = lane >> 4;
    const int colhalf = wid & 1, rowsub = wid >> 1;
    const int colbase = colhalf * 64;
    const int ro = rowsub * 16 + r;
    const int row = tile * 32 + ro;

    short8 hf[4];
    #pragma unroll
    for (int kc = 0; kc < 4; ++kc)
      hf[kc] = *(const short8*)(g + (size_t)row * 128 + kc * 32 + kg * 8);

    floatx4 acc[4];
    #pragma unroll
    for (int df = 0; df < 4; ++df) acc[df] = (floatx4){0.f, 0.f, 0.f, 0.f};

    const unsigned short* wp = WZ0 + (size_t)(colbase + r) * 128 + kg * 8;
    #pragma unroll
    for (int df = 0; df < 4; ++df) {
      #pragma unroll
      for (int kc = 0; kc < 4; ++kc) {
        short8 wf = *(const short8*)(wp + df * 2048 + kc * 32);
        acc[df] = __builtin_amdgcn_mfma_f32_16x16x32_bf16(wf, hf[kc], acc[df], 0, 0, 0);
      }
    }

    #pragma unroll
    for (int df = 0; df < 4; ++df) {
      float4 b4 = *(const float4*)&zb[colbase + df * 16 + kg * 4];
      union { unsigned short us[4]; uint2 u2; } o;
      o.us[0] = f2b(acc[df][0] + b4.x);
      o.us[1] = f2b(acc[df][1] + b4.y);
      o.us[2] = f2b(acc[df][2] + b4.z);
      o.us[3] = f2b(acc[df][3] + b4.w);
      int colb = (colbase + df * 16 + kg * 4) * 2;
      *(uint2*)(cs + ro * ROWB + (colb ^ ((ro & 7) << 4))) = o.u2;
    }
    __syncthreads();

    unsigned char* dstb = (unsigned char*)(zout + (size_t)tile * 32 * 128);
    #pragma unroll
    for (int i = 0; i < 2; ++i) {
      int byte = (i * 256 + tid) * 16;
      int ro2 = byte / ROWB;
      int colb2 = byte & (ROWB - 1);
      *(uint4*)(dstb + byte) =
          *(const uint4*)(cs + ro2 * ROWB + (colb2 ^ ((ro2 & 7) << 4)));
    }
  }
}

// ---------------- node GEMM via MFMA bf16, LDS-staged coalesced epilogue -------
__global__ __launch_bounds__(256) void gemm_z(
    const unsigned short* __restrict__ A,
    const unsigned short* __restrict__ Wt,
    const float* __restrict__ bias,
    unsigned short* __restrict__ C)
{
  constexpr int ROWB = 256;
  __shared__ __align__(16) unsigned char cs[32 * ROWB];

  const int tid = threadIdx.x;
  const int wid = tid >> 6, lane = tid & 63;
  const int r = lane & 15, kg = lane >> 4;
  const int colhalf = wid & 1, rowsub = wid >> 1;
  const int colbase = colhalf * 64;
  const int ro = rowsub * 16 + r;
  const int row = blockIdx.x * 32 + ro;

  short8 hf[4];
  #pragma unroll
  for (int kc = 0; kc < 4; ++kc)
    hf[kc] = *(const short8*)(A + (size_t)row * 128 + kc * 32 + kg * 8);

  floatx4 acc[4];
  #pragma unroll
  for (int df = 0; df < 4; ++df) acc[df] = (floatx4){0.f, 0.f, 0.f, 0.f};

  const unsigned short* wp = Wt + (size_t)(colbase + r) * 128 + kg * 8;
  #pragma unroll
  for (int df = 0; df < 4; ++df) {
    #pragma unroll
    for (int kc = 0; kc < 4; ++kc) {
      short8 wf = *(const short8*)(wp + df * 2048 + kc * 32);
      acc[df] = __builtin_amdgcn_mfma_f32_16x16x32_bf16(wf, hf[kc], acc[df], 0, 0, 0);
    }
  }

  #pragma unroll
  for (int df = 0; df < 4; ++df) {
    float4 b4 = *(const float4*)&bias[colbase + df * 16 + kg * 4];
    union { unsigned short us[4]; uint2 u2; } o;
    o.us[0] = f2b(acc[df][0] + b4.x);
    o.us[1] = f2b(acc[df][1] + b4.y);
    o.us[2] = f2b(acc[df][2] + b4.z);
    o.us[3] = f2b(acc[df][3] + b4.w);
    int colb = (colbase + df * 16 + kg * 4) * 2;
    *(uint2*)(cs + ro * ROWB + (colb ^ ((ro & 7) << 4))) = o.u2;
  }
  __syncthreads();

  unsigned char* dstb = (unsigned char*)(C + (size_t)blockIdx.x * 32 * 128);
  #pragma unroll
  for (int i = 0; i < 2; ++i) {
    int byte = (i * 256 + tid) * 16;
    int ro2 = byte / ROWB;
    int colb2 = byte & (ROWB - 1);
    *(uint4*)(dstb + byte) =
        *(const uint4*)(cs + ro2 * ROWB + (colb2 ^ ((ro2 & 7) << 4)));
  }
}

// ---------------- fused edge attention: score + softmax + g-aggregate ----------
// z pre-scaled by log2(e); score reduce via DPP (no DS-pipe on critical path).
__global__ __launch_bounds__(128) void edge_fused(
    const unsigned short* __restrict__ z, const unsigned short* __restrict__ g,
    const int* __restrict__ src, const int* __restrict__ row_start,
    unsigned short* __restrict__ gout)
{
  const int lane = threadIdx.x & 63;
  const int node = blockIdx.x * 2 + (threadIdx.x >> 6);
  const int sg = lane >> 4, sl = lane & 15;

  short8 qf = *(const short8*)(z + ((size_t)node << 7) + sl * 8);
  float qd[8];
  #pragma unroll
  for (int j = 0; j < 8; ++j) qd[j] = b2f((unsigned short)qf[j]);

  const int r0 = row_start[node], r1 = row_start[node + 1];

  float acc[8] = {0.f, 0.f, 0.f, 0.f, 0.f, 0.f, 0.f, 0.f};
  float ws = 0.f;

#define LOADG(VLD, HF, C)                                               \
  {                                                                     \
    int e_ = (C) + sg;                                                  \
    VLD = e_ < r1;                                                      \
    int s_ = VLD ? src[e_] : 0;                                         \
    HF = *(const short8*)(g + ((size_t)s_ << 7) + sl * 8);              \
  }

#define COMPG(VLD, HF)                                                  \
  {                                                                     \
    float hd_[8];                                                       \
    _Pragma("unroll")                                                   \
    for (int j = 0; j < 8; ++j) hd_[j] = b2f((unsigned short)HF[j]);    \
    float d0_ = 0.f, d1_ = 0.f;                                         \
    _Pragma("unroll")                                                   \
    for (int j = 0; j < 4; ++j) d0_ += qd[j] * hd_[j];                  \
    _Pragma("unroll")                                                   \
    for (int j = 4; j < 8; ++j) d1_ += qd[j] * hd_[j];                  \
    float d_ = row16_sum(d0_ + d1_);                                    \
    float w_ = VLD ? exp2f(d_) : 0.f;                                   \
    ws += w_;                                                           \
    _Pragma("unroll")                                                   \
    for (int j = 0; j < 8; ++j) acc[j] += w_ * hd_[j];                  \
  }

  bool vA, vB;
  short8 hA, hB;
  LOADG(vA, hA, r0);
  LOADG(vB, hB, r0 + 4);

  for (int c = r0; c < r1; c += 8) {
    bool vC, vD;
    short8 hC, hD;
    LOADG(vC, hC, c + 8);
    LOADG(vD, hD, c + 12);
    COMPG(vA, hA);
    COMPG(vB, hB);
    vA = vC; hA = hC;
    vB = vD; hB = hD;
  }

#undef LOADG
#undef COMPG

  #pragma unroll
  for (int off = 16; off <= 32; off <<= 1) {
    ws += __shfl_xor(ws, off, 64);
    #pragma unroll
    for (int j = 0; j < 8; ++j) acc[j] += __shfl_xor(acc[j], off, 64);
  }

  if (sg == 0) {
    float inv = (ws > 1e-20f) ? 1.0f / ws : 0.0f;
    union { unsigned short us[8]; uint4 u4; } o;
    #pragma unroll
    for (int j = 0; j < 8; ++j) o.us[j] = f2b(acc[j] * inv);
    *(uint4*)(gout + (size_t)node * 128 + sl * 8) = o.u4;
  }
}

// ---------------- output head via MFMA: logits + log_softmax -------------------
__global__ __launch_bounds__(256) void out_head_mfma(
    const unsigned short* __restrict__ h, const unsigned short* __restrict__ wout_t,
    const float* __restrict__ bout, float* __restrict__ out)
{
  __shared__ __align__(16) float os[64 * N_CLASSES];   // 10240 B

  const int wid = threadIdx.x >> 6, lane = threadIdx.x & 63;
  const int r = lane & 15, kg = lane >> 4;
  const int row_base = blockIdx.x * 64 + wid * 16;
  const int ar = row_base + r;

  floatx4 acc[3];
  #pragma unroll
  for (int n = 0; n < 3; ++n) acc[n] = (floatx4){0.f, 0.f, 0.f, 0.f};

  const unsigned short* ap = h + (size_t)ar * 128 + kg * 8;
  const unsigned short* bp = wout_t + (size_t)r * 128 + kg * 8;

  #pragma unroll
  for (int kc = 0; kc < 128; kc += 32) {
    short8 a0 = *(const short8*)(ap + kc);
    #pragma unroll
    for (int n = 0; n < 3; ++n) {
      short8 b = *(const short8*)(bp + n * 2048 + kc);
      acc[n] = __builtin_amdgcn_mfma_f32_16x16x32_bf16(a0, b, acc[n], 0, 0, 0);
    }
  }

  float bn0 = bout[r];
  float bn1 = bout[16 + r];
  float bn2 = (r < 8) ? bout[32 + r] : 0.f;

  #pragma unroll
  for (int g = 0; g < 4; ++g) {
    int rl = wid * 16 + kg * 4 + g;          // local row 0..63
    float l0 = acc[0][g] + bn0;
    float l1 = acc[1][g] + bn1;
    float l2 = acc[2][g] + bn2;              // valid only if r < 8
    float m = fmaxf(l0, l1);
    if (r < 8) m = fmaxf(m, l2);
    #pragma unroll
    for (int off = 8; off >= 1; off >>= 1) m = fmaxf(m, __shfl_xor(m, off, 64));
    float s = __expf(l0 - m) + __expf(l1 - m) + ((r < 8) ? __expf(l2 - m) : 0.f);
    #pragma unroll
    for (int off = 8; off >= 1; off >>= 1) s += __shfl_xor(s, off, 64);
    float lse = m + logf(s);
    os[rl * N_CLASSES + r]      = l0 - lse;
    os[rl * N_CLASSES + 16 + r] = l1 - lse;
    if (r < 8) os[rl * N_CLASSES + 32 + r] = l2 - lse;
  }
  __syncthreads();

  float* dstb = out + (size_t)blockIdx.x * 64 * N_CLASSES;
  #pragma unroll
  for (int i = 0; i < 3; ++i) {
    int idx = i * 256 + threadIdx.x;
    if (idx < 640)
      *(uint4*)(dstb + idx * 4) = *(const uint4*)(os + idx * 4);
  }
}

extern "C" void kernel_launch(void* const* d_in, const int* in_sizes, int n_in,
                              void* d_out, int out_size, void* d_ws, size_t ws_size,
                              hipStream_t stream) {
  const float* h_in = (const float*)d_in[0];
  const int*   src  = (const int*)d_in[1];
  const int*   dst  = (const int*)d_in[2];
  const float* Wq   = (const float*)d_in[3];
  const float* bq   = (const float*)d_in[4];
  const float* Wk   = (const float*)d_in[5];
  const float* bk   = (const float*)d_in[6];  // cancels in softmax (dst-constant)
  const float* Wv   = (const float*)d_in[7];
  const float* bv   = (const float*)d_in[8];
  const float* Wout = (const float*)d_in[9];
  const float* bout = (const float*)d_in[10];
  float* out = (float*)d_out;
  (void)bk;

  char* ws = (char*)d_ws;
  size_t off = 0;
  auto alloc = [&](size_t bytes) -> void* {
    void* p = ws + off;
    off += (bytes + 255) & ~(size_t)255;
    return p;
  };
  int*            row_start = (int*)           alloc((size_t)(N_NODES + 1) * sizeof(int));
  unsigned short* g0        = (unsigned short*)alloc((size_t)N_NODES * 128 * 2);
  unsigned short* g1        = (unsigned short*)alloc((size_t)N_NODES * 128 * 2);
  unsigned short* zbuf      = (unsigned short*)alloc((size_t)N_NODES * 128 * 2);
  unsigned short* WZ        = (unsigned short*)alloc((size_t)4 * 16384 * 2);
  unsigned short* WOt       = (unsigned short*)alloc((size_t)48 * 128 * 2);
  float*          D01  = (float*)alloc(16384 * 4);
  float*          D23  = (float*)alloc(16384 * 4);
  float*          A1f  = (float*)alloc(16384 * 4);
  float*          B1f  = (float*)alloc(16384 * 4);
  float*          E3   = (float*)alloc(16384 * 4);
  float*          F3   = (float*)alloc(16384 * 4);
  float*          A2f  = (float*)alloc(16384 * 4);
  float*          B2f  = (float*)alloc(16384 * 4);
  float*          A3f  = (float*)alloc(16384 * 4);
  float*          B3f  = (float*)alloc(16384 * 4);
  float*          C4f  = (float*)alloc(16384 * 4);
  float*          C3f  = (float*)alloc(16384 * 4);
  float*          zb   = (float*)alloc(4 * 128 * 4);
  float*          bout2 = (float*)alloc(64 * 4);

  auto J = [](const float* A, const float* B, float* Cf, unsigned short* Cb,
              float scale, int abt, int ncolsB, int storeT, int padrows) {
    MMJob j; j.A = A; j.B = B; j.Cf = Cf; j.Cb = Cb; j.scale = scale;
    j.abt = abt; j.ncolsB = ncolsB; j.storeT = storeT; j.padrows = padrows;
    return j;
  };
  const float* Wq_l[4] = {Wq, Wq + 16384, Wq + 32768, Wq + 49152};
  const float* Wk_l[4] = {Wk, Wk + 16384, Wk + 32768, Wk + 49152};
  const float* Wv_l[4] = {Wv, Wv + 16384, Wv + 32768, Wv + 49152};

  const float ZSC = SCALING * LOG2E;   // exp2 pre-scaling folded into WZ

  // stage 1: raw-input products
  MM7 s1;
  s1.j[0] = J(Wk_l[0], Wq_l[0], nullptr, WZ, ZSC, 1, 128, 0, 0);      // WZ0
  s1.j[1] = J(Wv_l[0], Wv_l[1], D01, nullptr, 1.f, 0, 128, 0, 0);
  s1.j[2] = J(Wv_l[2], Wv_l[3], D23, nullptr, 1.f, 0, 128, 0, 0);
  s1.j[3] = J(Wv_l[0], Wk_l[1], A1f, nullptr, 1.f, 0, 128, 0, 0);
  s1.j[4] = J(Wv_l[0], Wq_l[1], B1f, nullptr, 1.f, 0, 128, 0, 0);
  s1.j[5] = J(Wv_l[2], Wk_l[3], E3,  nullptr, 1.f, 0, 128, 0, 0);
  s1.j[6] = J(Wv_l[2], Wq_l[3], F3,  nullptr, 1.f, 0, 128, 0, 0);

  // stage 2
  MM7 s2;
  s2.j[0] = J(A1f, B1f, nullptr, WZ + 16384, ZSC, 1, 128, 0, 0);      // WZ1
  s2.j[1] = J(D01, Wk_l[2], A2f, nullptr, 1.f, 0, 128, 0, 0);
  s2.j[2] = J(D01, Wq_l[2], B2f, nullptr, 1.f, 0, 128, 0, 0);
  s2.j[3] = J(D01, E3, A3f, nullptr, 1.f, 0, 128, 0, 0);
  s2.j[4] = J(D01, F3, B3f, nullptr, 1.f, 0, 128, 0, 0);
  s2.j[5] = J(D01, D23, C4f, nullptr, 1.f, 0, 128, 0, 0);
  s2.j[6] = J(D01, Wv_l[2], C3f, nullptr, 1.f, 0, 128, 0, 0);

  // stage 3
  MM3 s3;
  s3.j[0] = J(A2f, B2f, nullptr, WZ + 32768, ZSC, 1, 128, 0, 0);      // WZ2
  s3.j[1] = J(A3f, B3f, nullptr, WZ + 49152, ZSC, 1, 128, 0, 0);      // WZ3
  s3.j[2] = J(C4f, Wout, nullptr, WOt, 1.f, 0, N_CLASSES, 1, 48);     // WOt

  setup_fold1<<<3106, 256, 0, stream>>>(h_in, dst, bq, Wk, g0, row_start, zb, s1);
  fold2<<<448, 256, 0, stream>>>(s2);
  fold3_z0<<<1443, 256, 0, stream>>>(s3, Wq, Wk, Wv, Wout, bq, bv, bout,
                                     D01, C3f, zb, bout2, g0, WZ, zbuf);

  // layer 0
  edge_fused<<<N_NODES / 2, 128, 0, stream>>>(zbuf, g0, src, row_start, g1);
  // layer 1
  gemm_z<<<1250, 256, 0, stream>>>(g1, WZ + 16384, zb + 128, zbuf);
  edge_fused<<<N_NODES / 2, 128, 0, stream>>>(zbuf, g1, src, row_start, g0);
  // layer 2
  gemm_z<<<1250, 256, 0, stream>>>(g0, WZ + 32768, zb + 256, zbuf);
  edge_fused<<<N_NODES / 2, 128, 0, stream>>>(zbuf, g0, src, row_start, g1);
  // layer 3
  gemm_z<<<1250, 256, 0, stream>>>(g1, WZ + 49152, zb + 384, zbuf);
  edge_fused<<<N_NODES / 2, 128, 0, stream>>>(zbuf, g1, src, row_start, g0);
  // head
  out_head_mfma<<<625, 256, 0, stream>>>(g0, WOt, bout2, out);
}

// Round 16
// 218.378 us; speedup vs baseline: 1.1674x; 1.0267x over previous
//
#include <hip/hip_runtime.h>
#include <math.h>

#define N_NODES 40000
#define N_EDGES 640000
#define HIDDEN 128
#define N_LAYERS 4
#define N_CLASSES 40
#define SCALING 0.08838834764831845f
#define LOG2E 1.4426950408889634f

typedef __attribute__((ext_vector_type(8))) short short8;
typedef __attribute__((ext_vector_type(4))) float floatx4;

static __device__ __forceinline__ float b2f(unsigned short u) {
  return __uint_as_float(((unsigned)u) << 16);
}
static __device__ __forceinline__ unsigned short f2b(float f) {
  unsigned u = __float_as_uint(f);
  u += 0x7fff + ((u >> 16) & 1);   // round-to-nearest-even
  return (unsigned short)(u >> 16);
}

// 16-lane (DPP row) sum: quad_perm xor1, xor2, then row_ror:4, row_ror:8.
// Pure VALU — no ds_bpermute on the score critical path.
static __device__ __forceinline__ float row16_sum(float d) {
  int x;
  x = __builtin_amdgcn_update_dpp(0, __float_as_int(d), 0xB1, 0xF, 0xF, true);
  d += __int_as_float(x);
  x = __builtin_amdgcn_update_dpp(0, __float_as_int(d), 0x4E, 0xF, 0xF, true);
  d += __int_as_float(x);
  x = __builtin_amdgcn_update_dpp(0, __float_as_int(d), 0x124, 0xF, 0xF, true);
  d += __int_as_float(x);
  x = __builtin_amdgcn_update_dpp(0, __float_as_int(d), 0x128, 0xF, 0xF, true);
  d += __int_as_float(x);
  return d;
}

// ---------------- f32 128x128 product jobs (weight folding) --------------------
struct MMJob {
  const float* A; const float* B;
  float* Cf; unsigned short* Cb;
  float scale;
  int abt; int ncolsB; int storeT; int padrows;
};
struct MM7 { MMJob j[7]; };
struct MM3 { MMJob j[3]; };

static __device__ __forceinline__ void run_job(const MMJob J, int bi) {
  int ty = threadIdx.x >> 7;        // 0..1
  int c  = threadIdx.x & 127;
  int r  = bi * 2 + ty;
  float acc = 0.f;
  if (J.abt) {
    const float* ar = J.A + (size_t)r * 128;
    const float* br = J.B + (size_t)c * 128;
    #pragma unroll 4
    for (int j = 0; j < 128; ++j) acc += ar[j] * br[j];
  } else if (c < J.ncolsB) {
    const float* ar = J.A + (size_t)r * 128;
    #pragma unroll 4
    for (int j = 0; j < 128; ++j) acc += ar[j] * J.B[(size_t)j * J.ncolsB + c];
  }
  acc *= J.scale;
  if (J.storeT) {
    if (c < J.ncolsB) {
      if (J.Cb) J.Cb[(size_t)c * 128 + r] = f2b(acc);
      else      J.Cf[(size_t)c * 128 + r] = acc;
    } else if (c < J.padrows && J.Cb) {
      J.Cb[(size_t)c * 128 + r] = 0;
    }
  } else if (c < J.ncolsB) {
    if (J.Cb) J.Cb[(size_t)r * J.ncolsB + c] = f2b(acc);
    else      J.Cf[(size_t)r * J.ncolsB + c] = acc;
  }
}

// ---------------- K1: setup (cast h0, CSR) + fold stage 1 + zb0 ----------------
__global__ __launch_bounds__(256) void setup_fold1(
    const float* __restrict__ h_in, const int* __restrict__ dst,
    const float* __restrict__ bq, const float* __restrict__ Wk,
    unsigned short* __restrict__ g0, int* __restrict__ row_start,
    float* __restrict__ zb, MM7 st)
{
  int blk = blockIdx.x;
  if (blk < 2657) {
    int idx = blk * 256 + threadIdx.x;
    if (idx < 640000) {
      const float4* p = (const float4*)h_in + (size_t)idx * 2;
      float4 a = p[0], b = p[1];
      union { unsigned short us[8]; uint4 v; } o;
      o.us[0] = f2b(a.x); o.us[1] = f2b(a.y); o.us[2] = f2b(a.z); o.us[3] = f2b(a.w);
      o.us[4] = f2b(b.x); o.us[5] = f2b(b.y); o.us[6] = f2b(b.z); o.us[7] = f2b(b.w);
      ((uint4*)g0)[idx] = o.v;
      return;
    }
    int c = idx - 640000;
    if (c <= N_NODES) {
      int lo = 0, hi = N_EDGES;
      while (lo < hi) {
        int mid = (lo + hi) >> 1;
        if (dst[mid] < c) lo = mid + 1; else hi = mid;
      }
      row_start[c] = lo;
    }
    return;
  }
  if (blk < 3105) {
    int b2 = blk - 2657;
    run_job(st.j[b2 >> 6], b2 & 63);
    return;
  }
  // zb layer 0 (exp2-prescaled): 2-way split dot, pipelined loads
  {
    __shared__ float part[2][128];
    int t = threadIdx.x, h = t >> 7, tt = t & 127;
    const float* wkr = Wk + (size_t)tt * 128 + h * 64;
    const float* bqh = bq + h * 64;
    float s = 0.f;
    #pragma unroll
    for (int o = 0; o < 64; ++o) s += bqh[o] * wkr[o];
    part[h][tt] = s;
    __syncthreads();
    if (t < 128) zb[t] = (part[0][t] + part[1][t]) * (SCALING * LOG2E);
  }
}

// ---------------- K2: fold stage 2 (7 jobs x 64 blocks) ------------------------
__global__ __launch_bounds__(256) void fold2(MM7 st) {
  run_job(st.j[blockIdx.x >> 6], blockIdx.x & 63);
}

// ---------------- K3: fold stage 3 + bias chain + gemm_z layer 0 ---------------
__global__ __launch_bounds__(256) void fold3_z0(
    MM3 st,
    const float* __restrict__ Wq, const float* __restrict__ Wk,
    const float* __restrict__ Wv, const float* __restrict__ Wout,
    const float* __restrict__ bq, const float* __restrict__ bv,
    const float* __restrict__ bout,
    const float* __restrict__ D01, const float* __restrict__ C3f,
    float* __restrict__ zb, float* __restrict__ bout2,
    const unsigned short* __restrict__ g, const unsigned short* __restrict__ WZ0,
    unsigned short* __restrict__ zout)
{
  int blk = blockIdx.x;
  if (blk < 192) {
    run_job(st.j[blk >> 6], blk & 63);
    return;
  }
  if (blk == 192) {
    // bias chain (zeros in this dataset, kept for exactness).
    int t = threadIdx.x, h = t >> 7, tt = t & 127;
    __shared__ float cb[128], v1[128], v2[128], part[2][128];
    if (t < 128) cb[t] = bv[t];
    __syncthreads();
    for (int l = 1; l < 4; ++l) {
      const float* Cvl = (l == 1) ? Wv : (l == 2 ? D01 : C3f);
      {
        const float* M = Wq + (size_t)l * 16384 + (size_t)h * 64 * 128 + tt;
        float s = 0.f;
        #pragma unroll
        for (int o = 0; o < 64; ++o) s += cb[h * 64 + o] * M[(size_t)o * 128];
        part[h][tt] = s;
        __syncthreads();
        if (t < 128) v1[t] = part[0][t] + part[1][t] + bq[(size_t)l * 128 + t];
        __syncthreads();
      }
      {
        const float* M = Wk + (size_t)l * 16384 + (size_t)tt * 128 + h * 64;
        float s = 0.f;
        #pragma unroll
        for (int o = 0; o < 64; ++o) s += v1[h * 64 + o] * M[o];
        part[h][tt] = s;
        __syncthreads();
        if (t < 128) v2[t] = part[0][t] + part[1][t];
        __syncthreads();
      }
      {
        const float* M = Cvl + (size_t)tt * 128 + h * 64;
        float s = 0.f;
        #pragma unroll
        for (int d = 0; d < 64; ++d) s += v2[h * 64 + d] * M[d];
        part[h][tt] = s;
        __syncthreads();
        if (t < 128)
          zb[(size_t)l * 128 + t] = (part[0][t] + part[1][t]) * (SCALING * LOG2E);
        __syncthreads();
      }
      {
        const float* M = Wv + (size_t)l * 16384 + (size_t)h * 64 * 128 + tt;
        float s = 0.f;
        #pragma unroll
        for (int d = 0; d < 64; ++d) s += cb[h * 64 + d] * M[(size_t)d * 128];
        part[h][tt] = s;
        __syncthreads();
        if (t < 128) cb[t] = part[0][t] + part[1][t] + bv[(size_t)l * 128 + t];
        __syncthreads();
      }
    }
    {
      float s = 0.f;
      if (tt < N_CLASSES) {
        const float* M = Wout + (size_t)h * 64 * N_CLASSES + tt;
        #pragma unroll
        for (int d = 0; d < 64; ++d) s += cb[h * 64 + d] * M[(size_t)d * N_CLASSES];
      }
      part[h][tt] = s;
      __syncthreads();
      if (t < N_CLASSES) bout2[t] = part[0][t] + part[1][t] + bout[t];
    }
    return;
  }

  // ---- gemm_z for layer 0 ----
  {
    const int tile = blk - 193;                 // 0..1249
    constexpr int ROWB = 256;
    __shared__ __align__(16) unsigned char cs[32 * ROWB];

    const int tid = threadIdx.x;
    const int wid = tid >> 6, lane = tid & 63;
    const int r = lane & 15, kg = lane >> 4;
    const int colhalf = wid & 1, rowsub = wid >> 1;
    const int colbase = colhalf * 64;
    const int ro = rowsub * 16 + r;
    const int row = tile * 32 + ro;

    short8 hf[4];
    #pragma unroll
    for (int kc = 0; kc < 4; ++kc)
      hf[kc] = *(const short8*)(g + (size_t)row * 128 + kc * 32 + kg * 8);

    floatx4 acc[4];
    #pragma unroll
    for (int df = 0; df < 4; ++df) acc[df] = (floatx4){0.f, 0.f, 0.f, 0.f};

    const unsigned short* wp = WZ0 + (size_t)(colbase + r) * 128 + kg * 8;
    #pragma unroll
    for (int df = 0; df < 4; ++df) {
      #pragma unroll
      for (int kc = 0; kc < 4; ++kc) {
        short8 wf = *(const short8*)(wp + df * 2048 + kc * 32);
        acc[df] = __builtin_amdgcn_mfma_f32_16x16x32_bf16(wf, hf[kc], acc[df], 0, 0, 0);
      }
    }

    #pragma unroll
    for (int df = 0; df < 4; ++df) {
      float4 b4 = *(const float4*)&zb[colbase + df * 16 + kg * 4];
      union { unsigned short us[4]; uint2 u2; } o;
      o.us[0] = f2b(acc[df][0] + b4.x);
      o.us[1] = f2b(acc[df][1] + b4.y);
      o.us[2] = f2b(acc[df][2] + b4.z);
      o.us[3] = f2b(acc[df][3] + b4.w);
      int colb = (colbase + df * 16 + kg * 4) * 2;
      *(uint2*)(cs + ro * ROWB + (colb ^ ((ro & 7) << 4))) = o.u2;
    }
    __syncthreads();

    unsigned char* dstb = (unsigned char*)(zout + (size_t)tile * 32 * 128);
    #pragma unroll
    for (int i = 0; i < 2; ++i) {
      int byte = (i * 256 + tid) * 16;
      int ro2 = byte / ROWB;
      int colb2 = byte & (ROWB - 1);
      *(uint4*)(dstb + byte) =
          *(const uint4*)(cs + ro2 * ROWB + (colb2 ^ ((ro2 & 7) << 4)));
    }
  }
}

// ---------------- node GEMM via MFMA bf16, LDS-staged coalesced epilogue -------
__global__ __launch_bounds__(256) void gemm_z(
    const unsigned short* __restrict__ A,
    const unsigned short* __restrict__ Wt,
    const float* __restrict__ bias,
    unsigned short* __restrict__ C)
{
  constexpr int ROWB = 256;
  __shared__ __align__(16) unsigned char cs[32 * ROWB];

  const int tid = threadIdx.x;
  const int wid = tid >> 6, lane = tid & 63;
  const int r = lane & 15, kg = lane >> 4;
  const int colhalf = wid & 1, rowsub = wid >> 1;
  const int colbase = colhalf * 64;
  const int ro = rowsub * 16 + r;
  const int row = blockIdx.x * 32 + ro;

  short8 hf[4];
  #pragma unroll
  for (int kc = 0; kc < 4; ++kc)
    hf[kc] = *(const short8*)(A + (size_t)row * 128 + kc * 32 + kg * 8);

  floatx4 acc[4];
  #pragma unroll
  for (int df = 0; df < 4; ++df) acc[df] = (floatx4){0.f, 0.f, 0.f, 0.f};

  const unsigned short* wp = Wt + (size_t)(colbase + r) * 128 + kg * 8;
  #pragma unroll
  for (int df = 0; df < 4; ++df) {
    #pragma unroll
    for (int kc = 0; kc < 4; ++kc) {
      short8 wf = *(const short8*)(wp + df * 2048 + kc * 32);
      acc[df] = __builtin_amdgcn_mfma_f32_16x16x32_bf16(wf, hf[kc], acc[df], 0, 0, 0);
    }
  }

  #pragma unroll
  for (int df = 0; df < 4; ++df) {
    float4 b4 = *(const float4*)&bias[colbase + df * 16 + kg * 4];
    union { unsigned short us[4]; uint2 u2; } o;
    o.us[0] = f2b(acc[df][0] + b4.x);
    o.us[1] = f2b(acc[df][1] + b4.y);
    o.us[2] = f2b(acc[df][2] + b4.z);
    o.us[3] = f2b(acc[df][3] + b4.w);
    int colb = (colbase + df * 16 + kg * 4) * 2;
    *(uint2*)(cs + ro * ROWB + (colb ^ ((ro & 7) << 4))) = o.u2;
  }
  __syncthreads();

  unsigned char* dstb = (unsigned char*)(C + (size_t)blockIdx.x * 32 * 128);
  #pragma unroll
  for (int i = 0; i < 2; ++i) {
    int byte = (i * 256 + tid) * 16;
    int ro2 = byte / ROWB;
    int colb2 = byte & (ROWB - 1);
    *(uint4*)(dstb + byte) =
        *(const uint4*)(cs + ro2 * ROWB + (colb2 ^ ((ro2 & 7) << 4)));
  }
}

// ---------------- fused edge attention: score + softmax + g-aggregate ----------
// z pre-scaled by log2(e); DPP score reduce; index stream prefetched 16 edges
// ahead so the src->row dependent chain never sits on the critical path.
__global__ __launch_bounds__(128) void edge_fused(
    const unsigned short* __restrict__ z, const unsigned short* __restrict__ g,
    const int* __restrict__ src, const int* __restrict__ row_start,
    unsigned short* __restrict__ gout)
{
  const int lane = threadIdx.x & 63;
  const int node = blockIdx.x * 2 + (threadIdx.x >> 6);
  const int sg = lane >> 4, sl = lane & 15;

  short8 qf = *(const short8*)(z + ((size_t)node << 7) + sl * 8);
  float qd[8];
  #pragma unroll
  for (int j = 0; j < 8; ++j) qd[j] = b2f((unsigned short)qf[j]);

  const int r0 = row_start[node], r1 = row_start[node + 1];

  float acc[8] = {0.f, 0.f, 0.f, 0.f, 0.f, 0.f, 0.f, 0.f};
  float ws = 0.f;

#define LOADI(VLD, IDX, C)                                              \
  {                                                                     \
    int e_ = (C) + sg;                                                  \
    VLD = e_ < r1;                                                      \
    IDX = VLD ? src[e_] : 0;                                            \
  }

#define LOADROW(HF, IDX)                                                \
  HF = *(const short8*)(g + ((size_t)(IDX) << 7) + sl * 8);

#define COMPG(VLD, HF)                                                  \
  {                                                                     \
    float hd_[8];                                                       \
    _Pragma("unroll")                                                   \
    for (int j = 0; j < 8; ++j) hd_[j] = b2f((unsigned short)HF[j]);    \
    float d0_ = 0.f, d1_ = 0.f;                                         \
    _Pragma("unroll")                                                   \
    for (int j = 0; j < 4; ++j) d0_ += qd[j] * hd_[j];                  \
    _Pragma("unroll")                                                   \
    for (int j = 4; j < 8; ++j) d1_ += qd[j] * hd_[j];                  \
    float d_ = row16_sum(d0_ + d1_);                                    \
    float w_ = VLD ? exp2f(d_) : 0.f;                                   \
    ws += w_;                                                           \
    _Pragma("unroll")                                                   \
    for (int j = 0; j < 8; ++j) acc[j] += w_ * hd_[j];                  \
  }

  bool vA, vB, vC, vD;
  int iA, iB, iC, iD;
  short8 hA, hB;
  LOADI(vA, iA, r0);
  LOADI(vB, iB, r0 + 4);
  LOADI(vC, iC, r0 + 8);
  LOADI(vD, iD, r0 + 12);
  LOADROW(hA, iA);
  LOADROW(hB, iB);

  for (int c = r0; c < r1; c += 8) {
    short8 hC, hD;
    LOADROW(hC, iC);                 // indices already resident
    LOADROW(hD, iD);
    bool vE, vF;
    int iE, iF;
    LOADI(vE, iE, c + 16);           // index stream runs 16 edges ahead
    LOADI(vF, iF, c + 20);
    COMPG(vA, hA);
    COMPG(vB, hB);
    vA = vC; hA = hC; vB = vD; hB = hD;
    vC = vE; iC = iE; vD = vF; iD = iF;
  }

#undef LOADI
#undef LOADROW
#undef COMPG

  #pragma unroll
  for (int off = 16; off <= 32; off <<= 1) {
    ws += __shfl_xor(ws, off, 64);
    #pragma unroll
    for (int j = 0; j < 8; ++j) acc[j] += __shfl_xor(acc[j], off, 64);
  }

  if (sg == 0) {
    float inv = (ws > 1e-20f) ? 1.0f / ws : 0.0f;
    union { unsigned short us[8]; uint4 u4; } o;
    #pragma unroll
    for (int j = 0; j < 8; ++j) o.us[j] = f2b(acc[j] * inv);
    *(uint4*)(gout + (size_t)node * 128 + sl * 8) = o.u4;
  }
}

// ---------------- output head via MFMA: logits + log_softmax -------------------
__global__ __launch_bounds__(256) void out_head_mfma(
    const unsigned short* __restrict__ h, const unsigned short* __restrict__ wout_t,
    const float* __restrict__ bout, float* __restrict__ out)
{
  __shared__ __align__(16) float os[64 * N_CLASSES];   // 10240 B

  const int wid = threadIdx.x >> 6, lane = threadIdx.x & 63;
  const int r = lane & 15, kg = lane >> 4;
  const int row_base = blockIdx.x * 64 + wid * 16;
  const int ar = row_base + r;

  floatx4 acc[3];
  #pragma unroll
  for (int n = 0; n < 3; ++n) acc[n] = (floatx4){0.f, 0.f, 0.f, 0.f};

  const unsigned short* ap = h + (size_t)ar * 128 + kg * 8;
  const unsigned short* bp = wout_t + (size_t)r * 128 + kg * 8;

  #pragma unroll
  for (int kc = 0; kc < 128; kc += 32) {
    short8 a0 = *(const short8*)(ap + kc);
    #pragma unroll
    for (int n = 0; n < 3; ++n) {
      short8 b = *(const short8*)(bp + n * 2048 + kc);
      acc[n] = __builtin_amdgcn_mfma_f32_16x16x32_bf16(a0, b, acc[n], 0, 0, 0);
    }
  }

  float bn0 = bout[r];
  float bn1 = bout[16 + r];
  float bn2 = (r < 8) ? bout[32 + r] : 0.f;

  #pragma unroll
  for (int g = 0; g < 4; ++g) {
    int rl = wid * 16 + kg * 4 + g;          // local row 0..63
    float l0 = acc[0][g] + bn0;
    float l1 = acc[1][g] + bn1;
    float l2 = acc[2][g] + bn2;              // valid only if r < 8
    float m = fmaxf(l0, l1);
    if (r < 8) m = fmaxf(m, l2);
    #pragma unroll
    for (int off = 8; off >= 1; off >>= 1) m = fmaxf(m, __shfl_xor(m, off, 64));
    float s = __expf(l0 - m) + __expf(l1 - m) + ((r < 8) ? __expf(l2 - m) : 0.f);
    #pragma unroll
    for (int off = 8; off >= 1; off >>= 1) s += __shfl_xor(s, off, 64);
    float lse = m + logf(s);
    os[rl * N_CLASSES + r]      = l0 - lse;
    os[rl * N_CLASSES + 16 + r] = l1 - lse;
    if (r < 8) os[rl * N_CLASSES + 32 + r] = l2 - lse;
  }
  __syncthreads();

  float* dstb = out + (size_t)blockIdx.x * 64 * N_CLASSES;
  #pragma unroll
  for (int i = 0; i < 3; ++i) {
    int idx = i * 256 + threadIdx.x;
    if (idx < 640)
      *(uint4*)(dstb + idx * 4) = *(const uint4*)(os + idx * 4);
  }
}

extern "C" void kernel_launch(void* const* d_in, const int* in_sizes, int n_in,
                              void* d_out, int out_size, void* d_ws, size_t ws_size,
                              hipStream_t stream) {
  const float* h_in = (const float*)d_in[0];
  const int*   src  = (const int*)d_in[1];
  const int*   dst  = (const int*)d_in[2];
  const float* Wq   = (const float*)d_in[3];
  const float* bq   = (const float*)d_in[4];
  const float* Wk   = (const float*)d_in[5];
  const float* bk   = (const float*)d_in[6];  // cancels in softmax (dst-constant)
  const float* Wv   = (const float*)d_in[7];
  const float* bv   = (const float*)d_in[8];
  const float* Wout = (const float*)d_in[9];
  const float* bout = (const float*)d_in[10];
  float* out = (float*)d_out;
  (void)bk;

  char* ws = (char*)d_ws;
  size_t off = 0;
  auto alloc = [&](size_t bytes) -> void* {
    void* p = ws + off;
    off += (bytes + 255) & ~(size_t)255;
    return p;
  };
  int*            row_start = (int*)           alloc((size_t)(N_NODES + 1) * sizeof(int));
  unsigned short* g0        = (unsigned short*)alloc((size_t)N_NODES * 128 * 2);
  unsigned short* g1        = (unsigned short*)alloc((size_t)N_NODES * 128 * 2);
  unsigned short* zbuf      = (unsigned short*)alloc((size_t)N_NODES * 128 * 2);
  unsigned short* WZ        = (unsigned short*)alloc((size_t)4 * 16384 * 2);
  unsigned short* WOt       = (unsigned short*)alloc((size_t)48 * 128 * 2);
  float*          D01  = (float*)alloc(16384 * 4);
  float*          D23  = (float*)alloc(16384 * 4);
  float*          A1f  = (float*)alloc(16384 * 4);
  float*          B1f  = (float*)alloc(16384 * 4);
  float*          E3   = (float*)alloc(16384 * 4);
  float*          F3   = (float*)alloc(16384 * 4);
  float*          A2f  = (float*)alloc(16384 * 4);
  float*          B2f  = (float*)alloc(16384 * 4);
  float*          A3f  = (float*)alloc(16384 * 4);
  float*          B3f  = (float*)alloc(16384 * 4);
  float*          C4f  = (float*)alloc(16384 * 4);
  float*          C3f  = (float*)alloc(16384 * 4);
  float*          zb   = (float*)alloc(4 * 128 * 4);
  float*          bout2 = (float*)alloc(64 * 4);

  auto J = [](const float* A, const float* B, float* Cf, unsigned short* Cb,
              float scale, int abt, int ncolsB, int storeT, int padrows) {
    MMJob j; j.A = A; j.B = B; j.Cf = Cf; j.Cb = Cb; j.scale = scale;
    j.abt = abt; j.ncolsB = ncolsB; j.storeT = storeT; j.padrows = padrows;
    return j;
  };
  const float* Wq_l[4] = {Wq, Wq + 16384, Wq + 32768, Wq + 49152};
  const float* Wk_l[4] = {Wk, Wk + 16384, Wk + 32768, Wk + 49152};
  const float* Wv_l[4] = {Wv, Wv + 16384, Wv + 32768, Wv + 49152};

  const float ZSC = SCALING * LOG2E;   // exp2 pre-scaling folded into WZ

  // stage 1: raw-input products
  MM7 s1;
  s1.j[0] = J(Wk_l[0], Wq_l[0], nullptr, WZ, ZSC, 1, 128, 0, 0);      // WZ0
  s1.j[1] = J(Wv_l[0], Wv_l[1], D01, nullptr, 1.f, 0, 128, 0, 0);
  s1.j[2] = J(Wv_l[2], Wv_l[3], D23, nullptr, 1.f, 0, 128, 0, 0);
  s1.j[3] = J(Wv_l[0], Wk_l[1], A1f, nullptr, 1.f, 0, 128, 0, 0);
  s1.j[4] = J(Wv_l[0], Wq_l[1], B1f, nullptr, 1.f, 0, 128, 0, 0);
  s1.j[5] = J(Wv_l[2], Wk_l[3], E3,  nullptr, 1.f, 0, 128, 0, 0);
  s1.j[6] = J(Wv_l[2], Wq_l[3], F3,  nullptr, 1.f, 0, 128, 0, 0);

  // stage 2
  MM7 s2;
  s2.j[0] = J(A1f, B1f, nullptr, WZ + 16384, ZSC, 1, 128, 0, 0);      // WZ1
  s2.j[1] = J(D01, Wk_l[2], A2f, nullptr, 1.f, 0, 128, 0, 0);
  s2.j[2] = J(D01, Wq_l[2], B2f, nullptr, 1.f, 0, 128, 0, 0);
  s2.j[3] = J(D01, E3, A3f, nullptr, 1.f, 0, 128, 0, 0);
  s2.j[4] = J(D01, F3, B3f, nullptr, 1.f, 0, 128, 0, 0);
  s2.j[5] = J(D01, D23, C4f, nullptr, 1.f, 0, 128, 0, 0);
  s2.j[6] = J(D01, Wv_l[2], C3f, nullptr, 1.f, 0, 128, 0, 0);

  // stage 3
  MM3 s3;
  s3.j[0] = J(A2f, B2f, nullptr, WZ + 32768, ZSC, 1, 128, 0, 0);      // WZ2
  s3.j[1] = J(A3f, B3f, nullptr, WZ + 49152, ZSC, 1, 128, 0, 0);      // WZ3
  s3.j[2] = J(C4f, Wout, nullptr, WOt, 1.f, 0, N_CLASSES, 1, 48);     // WOt

  setup_fold1<<<3106, 256, 0, stream>>>(h_in, dst, bq, Wk, g0, row_start, zb, s1);
  fold2<<<448, 256, 0, stream>>>(s2);
  fold3_z0<<<1443, 256, 0, stream>>>(s3, Wq, Wk, Wv, Wout, bq, bv, bout,
                                     D01, C3f, zb, bout2, g0, WZ, zbuf);

  // layer 0
  edge_fused<<<N_NODES / 2, 128, 0, stream>>>(zbuf, g0, src, row_start, g1);
  // layer 1
  gemm_z<<<1250, 256, 0, stream>>>(g1, WZ + 16384, zb + 128, zbuf);
  edge_fused<<<N_NODES / 2, 128, 0, stream>>>(zbuf, g1, src, row_start, g0);
  // layer 2
  gemm_z<<<1250, 256, 0, stream>>>(g0, WZ + 32768, zb + 256, zbuf);
  edge_fused<<<N_NODES / 2, 128, 0, stream>>>(zbuf, g0, src, row_start, g1);
  // layer 3
  gemm_z<<<1250, 256, 0, stream>>>(g1, WZ + 49152, zb + 384, zbuf);
  edge_fused<<<N_NODES / 2, 128, 0, stream>>>(zbuf, g1, src, row_start, g0);
  // head
  out_head_mfma<<<625, 256, 0, stream>>>(g0, WOt, bout2, out);
}